// Round 6
// baseline (1523.025 us; speedup 1.0000x reference)
//
#include <hip/hip_runtime.h>
#include <hip/hip_bf16.h>
#include <hip/hip_fp16.h>

#define NN  50000
#define NE  1600000
#define DIM 64
#define NBK 391          // 128-node buckets

// ---- ws layout (int32 offsets) -------------------------------------------
#define OFF_FLAGS  0            // 8 ints
#define OFF_BOFF   8            // 392: bucket counts -> exclusive offsets
#define OFF_BCUR   400          // 391 bucket cursors (pad to 792)
#define OFF_ROWPTR 792          // (unused now, kept for layout stability)
#define OFF_INP16  50800        // fp16 input stage (1.6M ints) when useH
#define OFF_RELW16 1650800      // fp16 relw stage (16384 ints) when useH
#define OFF_EIDX_H 1667184      // eidx when staged
// eidx at 50800 when not staged

#define CHUNK 4096   // edges per k_parta block

typedef __bf16 bf16x8 __attribute__((ext_vector_type(8)));
typedef float  f32x4  __attribute__((ext_vector_type(4)));

__device__ __forceinline__ float loadF(const void* p, int i, int bf) {
  if (bf) return __bfloat162float(((const __hip_bfloat16*)p)[i]);
  return ((const float*)p)[i];
}

__device__ __forceinline__ float4 loadF4(const void* p, int i4, int bf) {
  if (bf) {
    ushort4 u = ((const ushort4*)p)[i4];
    float4 f;
    union { unsigned int ui; float fl; } c;
    c.ui = (unsigned int)u.x << 16; f.x = c.fl;
    c.ui = (unsigned int)u.y << 16; f.y = c.fl;
    c.ui = (unsigned int)u.z << 16; f.z = c.fl;
    c.ui = (unsigned int)u.w << 16; f.w = c.fl;
    return f;
  }
  return ((const float4*)p)[i4];
}

__device__ __forceinline__ float4 h4f(ushort4 u) {
  float4 f;
  f.x = __half2float(__ushort_as_half(u.x));
  f.y = __half2float(__ushort_as_half(u.y));
  f.z = __half2float(__ushort_as_half(u.z));
  f.w = __half2float(__ushort_as_half(u.w));
  return f;
}

// Per-array dtype detection + zero bucket counts.
__global__ void k_detect(const void* input, const void* boundary,
                         const void* relw, const void* W, const void* ew,
                         int* flags, int* boff) {
  __shared__ int cnt;
  int t = threadIdx.x;  // 64 threads
  const void* arrs[4] = {input, boundary, relw, W};
  for (int a = 0; a < 4; ++a) {
    if (t == 0) cnt = 0;
    __syncthreads();
    const unsigned short* u = (const unsigned short*)arrs[a];
    unsigned ex = (u[2 * t] >> 7) & 0xFF;
    if (ex >= 100 && ex <= 140) atomicAdd(&cnt, 1);
    __syncthreads();
    if (t == 0) flags[a] = (cnt >= 32) ? 1 : 0;
    __syncthreads();
  }
  if (t == 0) {
    flags[4] = (((const unsigned short*)ew)[0] == 0x3F80) ? 1 : 0;
    flags[5] = 1;
  }
  for (int i = t; i < 392; i += 64) boff[i] = 0;
}

// Stage input + relw as fp16 (only when both are f32; hot path needs that).
__global__ __launch_bounds__(256) void k_stage(const void* __restrict__ in,
                                               const void* __restrict__ rw,
                                               unsigned short* __restrict__ inph,
                                               unsigned short* __restrict__ rwh,
                                               const int* __restrict__ flags) {
  if (flags[0] || flags[2]) return;   // non-f32 input/relw: hot path disabled
  int i = blockIdx.x * 256 + threadIdx.x;
  if (i < NN * 16) {
    float4 v = ((const float4*)in)[i];
    ushort4 h;
    h.x = __half_as_ushort(__float2half(v.x));
    h.y = __half_as_ushort(__float2half(v.y));
    h.z = __half_as_ushort(__float2half(v.z));
    h.w = __half_as_ushort(__float2half(v.w));
    ((ushort4*)inph)[i] = h;
  }
  if (i < 512 * 16) {
    float4 v = ((const float4*)rw)[i];
    ushort4 h;
    h.x = __half_as_ushort(__float2half(v.x));
    h.y = __half_as_ushort(__float2half(v.y));
    h.z = __half_as_ushort(__float2half(v.z));
    h.w = __half_as_ushort(__float2half(v.w));
    ((ushort4*)rwh)[i] = h;
  }
}

// Bucket-level histogram (LDS-privatized) + exact all-ones check of ew.
__global__ __launch_bounds__(256) void k_bhist(const int* __restrict__ el,
                                               const void* __restrict__ ew,
                                               int* __restrict__ bcnt,
                                               int* __restrict__ flags) {
  __shared__ int lc[NBK];
  int t = threadIdx.x;
  int bfE = flags[4];
  for (int i = t; i < NBK; i += 256) lc[i] = 0;
  __syncthreads();
  int c0 = blockIdx.x * 8192;
  int bad = 0;
  for (int i = t; i < 8192; i += 256) {
    int e = c0 + i;
    if (e < NE) {
      atomicAdd(&lc[el[e * 3 + 1] >> 7], 1);
      if (loadF(ew, e, bfE) != 1.0f) bad = 1;
    }
  }
  if (bad) flags[5] = 0;
  __syncthreads();
  for (int i = t; i < NBK; i += 256)
    if (lc[i]) atomicAdd(&bcnt[i], lc[i]);
}

// Exclusive scan of 392 bucket counts (pair trick); init cursors.
__global__ __launch_bounds__(256) void k_scanb(int* __restrict__ boff,
                                               int* __restrict__ bcur) {
  __shared__ int sc[256];
  int t = threadIdx.x;
  int i0 = 2 * t, i1 = 2 * t + 1;
  int a = (i0 < 392) ? boff[i0] : 0;
  int b = (i1 < 392) ? boff[i1] : 0;
  sc[t] = a + b;
  __syncthreads();
  for (int off = 1; off < 256; off <<= 1) {
    int v = (t >= off) ? sc[t - off] : 0;
    __syncthreads();
    sc[t] += v;
    __syncthreads();
  }
  int excl = sc[t] - (a + b);
  if (i0 < 392) boff[i0] = excl;
  if (i1 < 392) boff[i1] = excl + a;
  if (i0 < NBK) bcur[i0] = excl;
  if (i1 < NBK) bcur[i1] = excl + a;
}

// Partition edges into per-bucket regions via LDS staging (contiguous runs).
// rec = nin|rel<<16|local<<25 (ones) or e|local<<25 (generic).
__global__ __launch_bounds__(256) void k_parta(
    const int* __restrict__ el, int* __restrict__ bcur,
    int* __restrict__ eidx, const int* __restrict__ flags,
    const int* __restrict__ boff, int gb0, int gb1, int cap) {
  __shared__ int stage[CHUNK];
  __shared__ unsigned short sbk[CHUNK];
  __shared__ int lh[NBK], lbase[NBK], lh2[NBK], gbs[NBK];
  __shared__ int sc[256];
  __shared__ int total;
  int t = threadIdx.x;
  int nb = gb1 - gb0;
  int c0 = blockIdx.x * CHUNK;
  int ones = flags[5];
  int base0 = boff[gb0];
  for (int i = t; i < nb; i += 256) { lh[i] = 0; lh2[i] = 0; }
  __syncthreads();
  for (int i = t; i < CHUNK; i += 256) {
    int e = c0 + i;
    if (e < NE) {
      int b = (el[e * 3 + 1] >> 7) - gb0;
      if (b >= 0 && b < nb) atomicAdd(&lh[b], 1);
    }
  }
  __syncthreads();
  int a0 = (2 * t < nb) ? lh[2 * t] : 0;
  int a1 = (2 * t + 1 < nb) ? lh[2 * t + 1] : 0;
  sc[t] = a0 + a1;
  __syncthreads();
  for (int off = 1; off < 256; off <<= 1) {
    int v = (t >= off) ? sc[t - off] : 0;
    __syncthreads();
    sc[t] += v;
    __syncthreads();
  }
  int excl = sc[t] - (a0 + a1);
  if (2 * t < nb) {
    lbase[2 * t] = excl;
    if (a0 > 0) gbs[2 * t] = atomicAdd(&bcur[gb0 + 2 * t], a0);
  }
  if (2 * t + 1 < nb) {
    lbase[2 * t + 1] = excl + a0;
    if (a1 > 0) gbs[2 * t + 1] = atomicAdd(&bcur[gb0 + 2 * t + 1], a1);
  }
  if (t == 255) total = sc[255];
  __syncthreads();
  for (int i = t; i < CHUNK; i += 256) {
    int e = c0 + i;
    if (e < NE) {
      int nout = el[e * 3 + 1];
      int b = (nout >> 7) - gb0;
      if (b >= 0 && b < nb) {
        int r = atomicAdd(&lh2[b], 1);
        int slot = lbase[b] + r;
        int rec = ones ? (el[e * 3] | (el[e * 3 + 2] << 16) |
                          ((nout & 127) << 25))
                       : (e | ((nout & 127) << 25));
        stage[slot] = rec;
        sbk[slot] = (unsigned short)b;
      }
    }
  }
  __syncthreads();
  int tot = total;
  for (int i = t; i < tot; i += 256) {
    int b = sbk[i];
    int dst = gbs[b] + (i - lbase[b]) - base0;
    if (dst >= 0 && dst < cap) eidx[dst] = stage[i];
  }
}

// v6: edge-parallel LDS-accumulation node kernel. One block = one 64-node
// half-bucket. Streams bucket-grouped records (k_parta output, no node sort
// needed -> k_partb eliminated). Each 16-lane group gathers one edge's row
// pair and atomicAdds s/q into LDS f32 accumulators. No shfl chains, no
// per-node serial tiles (R1-R5: those were invariant while 4 param changes
// all nulled -> structure was the suspect).
__global__ __launch_bounds__(512, 8) void k_node(
    const void* __restrict__ input, const void* __restrict__ boundary,
    const int* __restrict__ el, const void* __restrict__ ew,
    const void* __restrict__ relw, const void* __restrict__ W,
    const void* __restrict__ bv, const int* __restrict__ boff,
    const int* __restrict__ eidx, const int* __restrict__ flags,
    const unsigned short* __restrict__ inph,
    const unsigned short* __restrict__ rwh,
    void* __restrict__ out, int gb0, int hi, int cap) {
  __shared__ float acc[64][130];    // [node][2*dim(+pad 2)]: s at 2d, q at 2d+1
  __shared__ float sdeg[64];
  __shared__ int   stage[512];
  __bf16 (*updb)[72] = reinterpret_cast<__bf16(*)[72]>(&acc[0][0]);

  int bfI = flags[0], bfB = flags[1], bfR = flags[2], bfW = flags[3],
      bfE = flags[4], ones = flags[5];
  int t = threadIdx.x;
  int B = gb0 + (blockIdx.x >> 1);
  unsigned h = blockIdx.x & 1;
  int n0g = B * 128 + (int)h * 64;
  int base0 = boff[gb0];
  int rbase = boff[B], rend = boff[B + 1];
  int cnt = rend - rbase;
  long lim = (long)cap - (rbase - base0);
  if (lim < 0) lim = 0;
  if ((long)cnt > lim) cnt = (int)lim;

  int gid = t >> 4;    // 32 groups of 16 lanes
  int k   = t & 15;    // float4 index within the 64-dim row

  for (int i = t; i < 64 * 130; i += 512) (&acc[0][0])[i] = 0.f;
  if (t < 64) sdeg[t] = 0.f;
  __syncthreads();

  const ushort4* ih4 = (const ushort4*)inph;
  const ushort4* rh4 = (const ushort4*)rwh;
  int hot = (!bfI && !bfR && ones && inph != 0) ? 1 : 0;

  for (int c0 = 0; c0 < cnt; c0 += 512) {
    int nrec = cnt - c0; if (nrec > 512) nrec = 512;
    if (t < nrec) stage[t] = eidx[rbase - base0 + c0 + t];
    __syncthreads();
    if (hot) {
      for (int i2 = gid; i2 < nrec; i2 += 32) {
        int rc = stage[i2];
        if ((((unsigned)rc) >> 31) != h) continue;
        int local = (rc >> 25) & 63;
        int nin = rc & 0xFFFF, rl = (rc >> 16) & 0x1FF;
        ushort4 ua = ih4[nin * 16 + k];
        ushort4 ur = rh4[rl * 16 + k];
        float4 a = h4f(ua), r = h4f(ur);
        float t0 = a.x * r.x, t1 = a.y * r.y, t2 = a.z * r.z, t3 = a.w * r.w;
        float* ap = &acc[local][8 * k];
        atomicAdd(ap + 0, t0); atomicAdd(ap + 1, t0 * t0);
        atomicAdd(ap + 2, t1); atomicAdd(ap + 3, t1 * t1);
        atomicAdd(ap + 4, t2); atomicAdd(ap + 5, t2 * t2);
        atomicAdd(ap + 6, t3); atomicAdd(ap + 7, t3 * t3);
        if (k == 0) atomicAdd(&sdeg[local], 1.0f);
      }
    } else {
      for (int i2 = gid; i2 < nrec; i2 += 32) {
        int rc = stage[i2];
        if ((((unsigned)rc) >> 31) != h) continue;
        int local = (rc >> 25) & 63;
        int nin, rl; float wj = 1.0f;
        if (ones) { nin = rc & 0xFFFF; rl = (rc >> 16) & 0x1FF; }
        else {
          int e = rc & 0x1FFFFFF;
          nin = el[e * 3]; rl = el[e * 3 + 2];
          wj = loadF(ew, e, bfE);
        }
        float4 a = loadF4(input, nin * 16 + k, bfI);
        float4 r = loadF4(relw,  rl * 16 + k, bfR);
        float t0 = wj * a.x * r.x, t1 = wj * a.y * r.y,
              t2 = wj * a.z * r.z, t3 = wj * a.w * r.w;
        float* ap = &acc[local][8 * k];
        atomicAdd(ap + 0, t0); atomicAdd(ap + 1, t0 * t0);
        atomicAdd(ap + 2, t1); atomicAdd(ap + 3, t1 * t1);
        atomicAdd(ap + 4, t2); atomicAdd(ap + 5, t2 * t2);
        atomicAdd(ap + 6, t3); atomicAdd(ap + 7, t3 * t3);
        if (k == 0) atomicAdd(&sdeg[local], 1.0f);
      }
    }
    __syncthreads();    // protect stage + acc chunk boundary
  }

  // ---- epilogue: u into registers (acc still live) ----
  int n2 = t >> 3, d0 = (t & 7) * 8;   // thread owns node n2, dims d0..d0+7
  int n = n0g + n2;
  float ureg[8];
  {
    float dg = sdeg[n2] + 1.0f;
    float4 b40 = {0.f,0.f,0.f,0.f}, b41 = {0.f,0.f,0.f,0.f};
    if (n < hi) {
      b40 = loadF4(boundary, n * 16 + (t & 7) * 2, bfB);
      b41 = loadF4(boundary, n * 16 + (t & 7) * 2 + 1, bfB);
    }
    float bb[8] = {b40.x, b40.y, b40.z, b40.w, b41.x, b41.y, b41.z, b41.w};
    #pragma unroll
    for (int j = 0; j < 8; ++j) {
      float s = acc[n2][2 * (d0 + j)]     + bb[j];
      float qq = acc[n2][2 * (d0 + j) + 1] + bb[j] * bb[j];
      float sv = s / dg, qv = qq / dg;
      ureg[j] = sqrtf(fmaxf(qv - sv * sv, 1e-6f));
    }
  }
  __syncthreads();                       // acc reads done; alias as updb
  #pragma unroll
  for (int j = 0; j < 8; ++j)
    updb[n2][d0 + j] = (n < hi) ? (__bf16)ureg[j] : (__bf16)0.f;
  __syncthreads();

  // ---- MFMA epilogue: 8 waves; wave wv -> node-tile wv>>1, col-half wv&1 --
  int wv = t >> 6, ln = t & 63, q = ln >> 4;
  int tt = wv >> 1, chh = wv & 1;
  bf16x8 af0 = *(const bf16x8*)&updb[tt * 16 + (ln & 15)][q * 8];
  bf16x8 af1 = *(const bf16x8*)&updb[tt * 16 + (ln & 15)][32 + q * 8];
  #pragma unroll
  for (int hh = 0; hh < 2; ++hh) {
    int cc = chh * 32 + hh * 16 + (ln & 15);
    bf16x8 bfr0, bfr1;
    #pragma unroll
    for (int j = 0; j < 8; ++j) {
      bfr0[j] = (__bf16)loadF(W, cc * 64 + q * 8 + j, bfW);
      bfr1[j] = (__bf16)loadF(W, cc * 64 + 32 + q * 8 + j, bfW);
    }
    float bias = loadF(bv, cc, bfW);
    f32x4 accv = {0.f, 0.f, 0.f, 0.f};
    accv = __builtin_amdgcn_mfma_f32_16x16x32_bf16(af0, bfr0, accv, 0, 0, 0);
    accv = __builtin_amdgcn_mfma_f32_16x16x32_bf16(af1, bfr1, accv, 0, 0, 0);
    #pragma unroll
    for (int i = 0; i < 4; ++i) {
      int nn = n0g + tt * 16 + q * 4 + i;
      if (nn < hi) {
        float v = accv[i] + bias;
        if (bfI) ((__hip_bfloat16*)out)[nn * 64 + cc] = __float2bfloat16(v);
        else     ((float*)out)[nn * 64 + cc] = v;
      }
    }
  }
}

extern "C" void kernel_launch(void* const* d_in, const int* in_sizes, int n_in,
                              void* d_out, int out_size, void* d_ws, size_t ws_size,
                              hipStream_t stream) {
  const void* input    = d_in[0];
  const void* boundary = d_in[1];
  const int*  edges    = (const int*)d_in[2];
  const void* eweight  = d_in[3];
  const void* relw     = d_in[4];
  const void* W        = d_in[5];
  const void* bv       = d_in[6];

  int* wsI    = (int*)d_ws;
  int* flags  = wsI + OFF_FLAGS;
  int* boff   = wsI + OFF_BOFF;
  int* bcur   = wsI + OFF_BCUR;

  long avail = (long)(ws_size / 4) - OFF_INP16;
  int useH = (avail >= (long)NE + 1600000 + 16384) ? 1 : 0;
  unsigned short* inph = useH ? (unsigned short*)(wsI + OFF_INP16) : 0;
  unsigned short* rwh  = useH ? (unsigned short*)(wsI + OFF_RELW16) : 0;
  int* eidx = useH ? (wsI + OFF_EIDX_H) : (wsI + OFF_INP16);
  long cap = useH ? (avail - 1600000 - 16384) : avail;
  if (cap < 1) cap = 1;
  int npass;
  if      (cap >= (long)NE) npass = 1;
  else if (cap >= 1000000)  npass = 2;
  else if (cap >= 520000)   npass = 4;
  else                      npass = 8;

  k_detect<<<1, 64, 0, stream>>>(input, boundary, relw, W, eweight,
                                 flags, boff);
  if (useH)
    k_stage<<<(NN * 16 + 255) / 256, 256, 0, stream>>>(input, relw, inph,
                                                       rwh, flags);
  k_bhist<<<(NE + 8191) / 8192, 256, 0, stream>>>(edges, eweight, boff, flags);
  k_scanb<<<1, 256, 0, stream>>>(boff, bcur);

  const int PA_NB = (NE + CHUNK - 1) / CHUNK;
  for (int p = 0; p < npass; ++p) {
    int gb0 = NBK * p / npass;
    int gb1 = NBK * (p + 1) / npass;
    int hi = (gb1 * 128 < NN) ? gb1 * 128 : NN;
    k_parta<<<PA_NB, 256, 0, stream>>>(edges, bcur, eidx, flags, boff,
                                       gb0, gb1, (int)cap);
    k_node<<<(gb1 - gb0) * 2, 512, 0, stream>>>(
        input, boundary, edges, eweight, relw, W, bv, boff, eidx, flags,
        inph, rwh, d_out, gb0, hi, (int)cap);
  }
}

// Round 7
// 241.062 us; speedup vs baseline: 6.3180x; 6.3180x over previous
//
#include <hip/hip_runtime.h>
#include <hip/hip_bf16.h>
#include <hip/hip_fp16.h>

#define NN  50000
#define NE  1600000
#define DIM 64
#define NBK 391          // 128-node buckets

// ---- ws layout (int32 offsets) -------------------------------------------
#define OFF_FLAGS  0            // 8 ints
#define OFF_BOFF   8            // 392: bucket counts -> exclusive offsets
#define OFF_BCUR   400          // 391 bucket cursors (pad to 792)
#define OFF_INP16  50800        // fp16 input stage (1.6M ints) when useH
#define OFF_RELW16 1650800      // fp16 relw stage (16384 ints) when useH
#define OFF_EIDX_H 1667184      // eidx when staged
// eidx at 50800 when not staged

#define CHUNK 4096   // edges per k_parta block
#define SBCAP 7936   // in-LDS sort capacity (expected bucket ~4092)

typedef __bf16 bf16x8 __attribute__((ext_vector_type(8)));
typedef __bf16 bf16x4 __attribute__((ext_vector_type(4)));
typedef float  f32x4  __attribute__((ext_vector_type(4)));

__device__ __forceinline__ float loadF(const void* p, int i, int bf) {
  if (bf) return __bfloat162float(((const __hip_bfloat16*)p)[i]);
  return ((const float*)p)[i];
}

__device__ __forceinline__ float4 loadF4(const void* p, int i4, int bf) {
  if (bf) {
    ushort4 u = ((const ushort4*)p)[i4];
    float4 f;
    union { unsigned int ui; float fl; } c;
    c.ui = (unsigned int)u.x << 16; f.x = c.fl;
    c.ui = (unsigned int)u.y << 16; f.y = c.fl;
    c.ui = (unsigned int)u.z << 16; f.z = c.fl;
    c.ui = (unsigned int)u.w << 16; f.w = c.fl;
    return f;
  }
  return ((const float4*)p)[i4];
}

__device__ __forceinline__ float4 h4f(ushort4 u) {
  float4 f;
  f.x = __half2float(__ushort_as_half(u.x));
  f.y = __half2float(__ushort_as_half(u.y));
  f.z = __half2float(__ushort_as_half(u.z));
  f.w = __half2float(__ushort_as_half(u.w));
  return f;
}

__device__ __forceinline__ void accum(ushort4 ua, ushort4 ur,
                                      float4& s4, float4& q4) {
  float4 a = h4f(ua), r = h4f(ur);
  float tx = a.x * r.x, ty = a.y * r.y, tz = a.z * r.z, tw = a.w * r.w;
  s4.x += tx; q4.x = fmaf(tx, tx, q4.x);
  s4.y += ty; q4.y = fmaf(ty, ty, q4.y);
  s4.z += tz; q4.z = fmaf(tz, tz, q4.z);
  s4.w += tw; q4.w = fmaf(tw, tw, q4.w);
}

// Per-array dtype detection + zero bucket counts.
__global__ void k_detect(const void* input, const void* boundary,
                         const void* relw, const void* W, const void* ew,
                         int* flags, int* boff) {
  __shared__ int cnt;
  int t = threadIdx.x;  // 64 threads
  const void* arrs[4] = {input, boundary, relw, W};
  for (int a = 0; a < 4; ++a) {
    if (t == 0) cnt = 0;
    __syncthreads();
    const unsigned short* u = (const unsigned short*)arrs[a];
    unsigned ex = (u[2 * t] >> 7) & 0xFF;
    if (ex >= 100 && ex <= 140) atomicAdd(&cnt, 1);
    __syncthreads();
    if (t == 0) flags[a] = (cnt >= 32) ? 1 : 0;
    __syncthreads();
  }
  if (t == 0) {
    flags[4] = (((const unsigned short*)ew)[0] == 0x3F80) ? 1 : 0;
    flags[5] = 1;
  }
  for (int i = t; i < 392; i += 64) boff[i] = 0;
}

// Stage input + relw as fp16 (only when both are f32; hot path needs that).
__global__ __launch_bounds__(256) void k_stage(const void* __restrict__ in,
                                               const void* __restrict__ rw,
                                               unsigned short* __restrict__ inph,
                                               unsigned short* __restrict__ rwh,
                                               const int* __restrict__ flags) {
  if (flags[0] || flags[2]) return;   // non-f32 input/relw: hot path disabled
  int i = blockIdx.x * 256 + threadIdx.x;
  if (i < NN * 16) {
    float4 v = ((const float4*)in)[i];
    ushort4 h;
    h.x = __half_as_ushort(__float2half(v.x));
    h.y = __half_as_ushort(__float2half(v.y));
    h.z = __half_as_ushort(__float2half(v.z));
    h.w = __half_as_ushort(__float2half(v.w));
    ((ushort4*)inph)[i] = h;
  }
  if (i < 512 * 16) {
    float4 v = ((const float4*)rw)[i];
    ushort4 h;
    h.x = __half_as_ushort(__float2half(v.x));
    h.y = __half_as_ushort(__float2half(v.y));
    h.z = __half_as_ushort(__float2half(v.z));
    h.w = __half_as_ushort(__float2half(v.w));
    ((ushort4*)rwh)[i] = h;
  }
}

// Bucket-level histogram (LDS-privatized) + exact all-ones check of ew.
__global__ __launch_bounds__(256) void k_bhist(const int* __restrict__ el,
                                               const void* __restrict__ ew,
                                               int* __restrict__ bcnt,
                                               int* __restrict__ flags) {
  __shared__ int lc[NBK];
  int t = threadIdx.x;
  int bfE = flags[4];
  for (int i = t; i < NBK; i += 256) lc[i] = 0;
  __syncthreads();
  int c0 = blockIdx.x * 8192;
  int bad = 0;
  for (int i = t; i < 8192; i += 256) {
    int e = c0 + i;
    if (e < NE) {
      atomicAdd(&lc[el[e * 3 + 1] >> 7], 1);
      if (loadF(ew, e, bfE) != 1.0f) bad = 1;
    }
  }
  if (bad) flags[5] = 0;
  __syncthreads();
  for (int i = t; i < NBK; i += 256)
    if (lc[i]) atomicAdd(&bcnt[i], lc[i]);
}

// Exclusive scan of 392 bucket counts (pair trick); init cursors.
__global__ __launch_bounds__(256) void k_scanb(int* __restrict__ boff,
                                               int* __restrict__ bcur) {
  __shared__ int sc[256];
  int t = threadIdx.x;
  int i0 = 2 * t, i1 = 2 * t + 1;
  int a = (i0 < 392) ? boff[i0] : 0;
  int b = (i1 < 392) ? boff[i1] : 0;
  sc[t] = a + b;
  __syncthreads();
  for (int off = 1; off < 256; off <<= 1) {
    int v = (t >= off) ? sc[t - off] : 0;
    __syncthreads();
    sc[t] += v;
    __syncthreads();
  }
  int excl = sc[t] - (a + b);
  if (i0 < 392) boff[i0] = excl;
  if (i1 < 392) boff[i1] = excl + a;
  if (i0 < NBK) bcur[i0] = excl;
  if (i1 < NBK) bcur[i1] = excl + a;
}

// Partition edges into per-bucket regions via LDS staging (contiguous runs).
// rec = nin|rel<<16|local<<25 (ones) or e|local<<25 (generic).
__global__ __launch_bounds__(256) void k_parta(
    const int* __restrict__ el, int* __restrict__ bcur,
    int* __restrict__ eidx, const int* __restrict__ flags,
    const int* __restrict__ boff, int gb0, int gb1, int cap) {
  __shared__ int stage[CHUNK];
  __shared__ unsigned short sbk[CHUNK];
  __shared__ int lh[NBK], lbase[NBK], lh2[NBK], gbs[NBK];
  __shared__ int sc[256];
  __shared__ int total;
  int t = threadIdx.x;
  int nb = gb1 - gb0;
  int c0 = blockIdx.x * CHUNK;
  int ones = flags[5];
  int base0 = boff[gb0];
  for (int i = t; i < nb; i += 256) { lh[i] = 0; lh2[i] = 0; }
  __syncthreads();
  for (int i = t; i < CHUNK; i += 256) {
    int e = c0 + i;
    if (e < NE) {
      int b = (el[e * 3 + 1] >> 7) - gb0;
      if (b >= 0 && b < nb) atomicAdd(&lh[b], 1);
    }
  }
  __syncthreads();
  int a0 = (2 * t < nb) ? lh[2 * t] : 0;
  int a1 = (2 * t + 1 < nb) ? lh[2 * t + 1] : 0;
  sc[t] = a0 + a1;
  __syncthreads();
  for (int off = 1; off < 256; off <<= 1) {
    int v = (t >= off) ? sc[t - off] : 0;
    __syncthreads();
    sc[t] += v;
    __syncthreads();
  }
  int excl = sc[t] - (a0 + a1);
  if (2 * t < nb) {
    lbase[2 * t] = excl;
    if (a0 > 0) gbs[2 * t] = atomicAdd(&bcur[gb0 + 2 * t], a0);
  }
  if (2 * t + 1 < nb) {
    lbase[2 * t + 1] = excl + a0;
    if (a1 > 0) gbs[2 * t + 1] = atomicAdd(&bcur[gb0 + 2 * t + 1], a1);
  }
  if (t == 255) total = sc[255];
  __syncthreads();
  for (int i = t; i < CHUNK; i += 256) {
    int e = c0 + i;
    if (e < NE) {
      int nout = el[e * 3 + 1];
      int b = (nout >> 7) - gb0;
      if (b >= 0 && b < nb) {
        int r = atomicAdd(&lh2[b], 1);
        int slot = lbase[b] + r;
        int rec = ones ? (el[e * 3] | (el[e * 3 + 2] << 16) |
                          ((nout & 127) << 25))
                       : (e | ((nout & 127) << 25));
        stage[slot] = rec;
        sbk[slot] = (unsigned short)b;
      }
    }
  }
  __syncthreads();
  int tot = total;
  for (int i = t; i < tot; i += 256) {
    int b = sbk[i];
    int dst = gbs[b] + (i - lbase[b]) - base0;
    if (dst >= 0 && dst < cap) eidx[dst] = stage[i];
  }
}

// v7: fused sort+node kernel. One 1024-thread block = one 128-node bucket
// (16 waves -> ~24 waves/CU at 391 blocks; fixes the old 256-thread fusion's
// 16%-occupancy failure). In-LDS counting sort (ld -> ld2), then R5's proven
// 87us edge phase reading sorted records from LDS. eidx read once; k_partb,
// rowptr, and one launch eliminated.
__global__ __launch_bounds__(1024, 8) void k_node(
    const void* __restrict__ input, const void* __restrict__ boundary,
    const int* __restrict__ el, const void* __restrict__ ew,
    const void* __restrict__ relw, const void* __restrict__ W,
    const void* __restrict__ bv, const int* __restrict__ boff,
    const int* __restrict__ eidx, const int* __restrict__ flags,
    const unsigned short* __restrict__ inph,
    const unsigned short* __restrict__ rwh,
    void* __restrict__ out, int gb0, int hi, int cap) {
  __shared__ int ld[SBCAP];     // raw records; aliased as updb after scatter
  __shared__ int ld2[SBCAP];    // node-sorted records
  __shared__ int lstart[128], lend[128], lcnt[128];
  __bf16 (*updb)[72] = reinterpret_cast<__bf16(*)[72]>(ld);

  int bfI = flags[0], bfB = flags[1], bfR = flags[2], bfW = flags[3],
      bfE = flags[4], ones = flags[5];
  int t = threadIdx.x;
  int wv = t >> 6, ln = t & 63;
  int g = ln >> 4;           // edge sub-slot group
  int k = ln & 15;           // float4 index within the 64-dim row
  int q = ln >> 4;
  int B = gb0 + blockIdx.x;
  int n0 = B * 128;
  int base0 = boff[gb0];
  int rbase = boff[B], rend = boff[B + 1];
  int cnt = rend - rbase;
  int fast = (cnt <= SBCAP) && (rend - base0 <= cap);

  if (t < 128) lcnt[t] = 0;
  __syncthreads();
  if (fast) {
    for (int i = t; i < cnt; i += 1024) ld[i] = eidx[rbase - base0 + i];
    __syncthreads();
    for (int i = t; i < cnt; i += 1024)
      atomicAdd(&lcnt[(((unsigned)ld[i]) >> 25) & 127], 1);
  }
  __syncthreads();
  // inclusive scan of lcnt in lend
  if (t < 128) lend[t] = lcnt[t];
  __syncthreads();
  for (int off = 1; off < 128; off <<= 1) {
    int v = 0;
    if (t < 128 && t >= off) v = lend[t - off];
    __syncthreads();
    if (t < 128) lend[t] += v;
    __syncthreads();
  }
  if (t < 128) { lstart[t] = lend[t] - lcnt[t]; lcnt[t] = 0; }
  __syncthreads();
  if (fast) {
    for (int i = t; i < cnt; i += 1024) {
      int rec = ld[i];
      int l = (((unsigned)rec) >> 25) & 127;
      int r = atomicAdd(&lcnt[l], 1);
      ld2[lstart[l] + r] = rec;
    }
  }
  __syncthreads();   // ld dead from here -> safe to alias as updb

  const ushort4* ih4 = (const ushort4*)inph;
  const ushort4* rh4 = (const ushort4*)rwh;
  int hot = (!bfI && !bfR && ones && inph != 0) ? 1 : 0;

  // ---- edge phase: 8 nodes per wave ----
  for (int rr = 0; rr < 8; ++rr) {
    int row = wv * 8 + rr;
    int n = n0 + row;
    if (n >= hi) {
      if (g == 0) *(bf16x4*)&updb[row][4 * k] =
          bf16x4{(__bf16)0.f, (__bf16)0.f, (__bf16)0.f, (__bf16)0.f};
      continue;
    }
    float4 s4 = {0.f,0.f,0.f,0.f}, q4 = {0.f,0.f,0.f,0.f};
    float degf = 0.f;
    if (fast) {
      int start = lstart[row], end = lend[row];
      degf = (float)(end - start);
      if (hot) {
        for (int base = start; base < end; base += 64) {
          int mm = end - base; if (mm > 64) mm = 64;
          int rec = 0;
          if (ln < mm) rec = ld2[base + ln];
          int jq = mm >> 2;
          int jmax = (mm + 3) >> 2;
          int j = 0;
          for (; j + 4 <= jq; j += 4) {   // 16 edges per iter
            int pk0 = __shfl(rec, j * 4 + g);
            int pk1 = __shfl(rec, j * 4 + 4 + g);
            int pk2 = __shfl(rec, j * 4 + 8 + g);
            int pk3 = __shfl(rec, j * 4 + 12 + g);
            ushort4 a0 = ih4[(pk0 & 0xFFFF) * 16 + k];
            ushort4 r0 = rh4[((pk0 >> 16) & 0x1FF) * 16 + k];
            ushort4 a1 = ih4[(pk1 & 0xFFFF) * 16 + k];
            ushort4 r1 = rh4[((pk1 >> 16) & 0x1FF) * 16 + k];
            ushort4 a2 = ih4[(pk2 & 0xFFFF) * 16 + k];
            ushort4 r2 = rh4[((pk2 >> 16) & 0x1FF) * 16 + k];
            ushort4 a3 = ih4[(pk3 & 0xFFFF) * 16 + k];
            ushort4 r3 = rh4[((pk3 >> 16) & 0x1FF) * 16 + k];
            accum(a0, r0, s4, q4);
            accum(a1, r1, s4, q4);
            accum(a2, r2, s4, q4);
            accum(a3, r3, s4, q4);
          }
          for (; j < jq; ++j) {
            int pk = __shfl(rec, j * 4 + g);
            ushort4 a = ih4[(pk & 0xFFFF) * 16 + k];
            ushort4 r = rh4[((pk >> 16) & 0x1FF) * 16 + k];
            accum(a, r, s4, q4);
          }
          for (; j < jmax; ++j) {      // predicated tail (<=1 iter)
            int slot = j * 4 + g;
            int pk = __shfl(rec, slot & 63);
            float wsel = (slot < mm) ? 1.0f : 0.0f;
            ushort4 ua = ih4[(pk & 0xFFFF) * 16 + k];
            ushort4 ur = rh4[((pk >> 16) & 0x1FF) * 16 + k];
            float4 a = h4f(ua), r = h4f(ur);
            float tx = a.x*r.x, ty = a.y*r.y, tz = a.z*r.z, tw = a.w*r.w;
            s4.x = fmaf(wsel, tx, s4.x); q4.x = fmaf(wsel*tx, tx, q4.x);
            s4.y = fmaf(wsel, ty, s4.y); q4.y = fmaf(wsel*ty, ty, q4.y);
            s4.z = fmaf(wsel, tz, s4.z); q4.z = fmaf(wsel*tz, tz, q4.z);
            s4.w = fmaf(wsel, tw, s4.w); q4.w = fmaf(wsel*tw, tw, q4.w);
          }
        }
      } else {
        for (int base = start; base < end; base += 64) {
          int mm = end - base; if (mm > 64) mm = 64;
          int rec = 0; float wrec = 0.0f;
          if (ln < mm) {
            rec = ld2[base + ln] & 0x1FFFFFF;
            if (!ones) wrec = loadF(ew, rec, bfE);
          }
          int jmax = (mm + 3) >> 2;
          for (int j = 0; j < jmax; ++j) {
            int slot = j * 4 + g;
            int rj = __shfl(rec, slot);
            int nin, rl; float wj;
            if (ones) { nin = rj & 0xFFFF; rl = (rj >> 16) & 0x1FF; wj = 1.0f; }
            else      { nin = el[rj * 3]; rl = el[rj * 3 + 2];
                        wj = __shfl(wrec, slot); }
            float wsel = (slot < mm) ? wj : 0.0f;
            float4 a = loadF4(input, nin * 16 + k, bfI);
            float4 r = loadF4(relw, rl * 16 + k, bfR);
            float tx = a.x*r.x, ty = a.y*r.y, tz = a.z*r.z, tw = a.w*r.w;
            s4.x = fmaf(wsel, tx, s4.x); q4.x = fmaf(wsel*tx, tx, q4.x);
            s4.y = fmaf(wsel, ty, s4.y); q4.y = fmaf(wsel*ty, ty, q4.y);
            s4.z = fmaf(wsel, tz, s4.z); q4.z = fmaf(wsel*tz, tz, q4.z);
            s4.w = fmaf(wsel, tw, s4.w); q4.w = fmaf(wsel*tw, tw, q4.w);
          }
        }
      }
    } else {
      // correctness-only fallback: scan full edge list for this node
      float degc = 0.f;
      for (int e0 = g; e0 < NE; e0 += 4) {
        int nout = el[e0 * 3 + 1];
        if (nout != n) continue;
        degc += 1.0f;
        int nin = el[e0 * 3], rl = el[e0 * 3 + 2];
        float wj = ones ? 1.0f : loadF(ew, e0, bfE);
        float4 a = loadF4(input, nin * 16 + k, bfI);
        float4 r = loadF4(relw, rl * 16 + k, bfR);
        float tx = wj*a.x*r.x, ty = wj*a.y*r.y, tz = wj*a.z*r.z,
              tw = wj*a.w*r.w;
        s4.x += tx; q4.x = fmaf(tx, tx, q4.x);
        s4.y += ty; q4.y = fmaf(ty, ty, q4.y);
        s4.z += tz; q4.z = fmaf(tz, tz, q4.z);
        s4.w += tw; q4.w = fmaf(tw, tw, q4.w);
      }
      degc += __shfl_xor(degc, 16); degc += __shfl_xor(degc, 32);
      degf = degc;
    }
    s4.x += __shfl_xor(s4.x, 16); s4.x += __shfl_xor(s4.x, 32);
    s4.y += __shfl_xor(s4.y, 16); s4.y += __shfl_xor(s4.y, 32);
    s4.z += __shfl_xor(s4.z, 16); s4.z += __shfl_xor(s4.z, 32);
    s4.w += __shfl_xor(s4.w, 16); s4.w += __shfl_xor(s4.w, 32);
    q4.x += __shfl_xor(q4.x, 16); q4.x += __shfl_xor(q4.x, 32);
    q4.y += __shfl_xor(q4.y, 16); q4.y += __shfl_xor(q4.y, 32);
    q4.z += __shfl_xor(q4.z, 16); q4.z += __shfl_xor(q4.z, 32);
    q4.w += __shfl_xor(q4.w, 16); q4.w += __shfl_xor(q4.w, 32);
    if (g == 0) {
      float4 b4 = loadF4(boundary, n * 16 + k, bfB);
      float dg = degf + 1.0f;
      float sv, qv;
      bf16x4 u;
      sv = (s4.x + b4.x) / dg; qv = (q4.x + b4.x * b4.x) / dg;
      u[0] = (__bf16)sqrtf(fmaxf(qv - sv * sv, 1e-6f));
      sv = (s4.y + b4.y) / dg; qv = (q4.y + b4.y * b4.y) / dg;
      u[1] = (__bf16)sqrtf(fmaxf(qv - sv * sv, 1e-6f));
      sv = (s4.z + b4.z) / dg; qv = (q4.z + b4.z * b4.z) / dg;
      u[2] = (__bf16)sqrtf(fmaxf(qv - sv * sv, 1e-6f));
      sv = (s4.w + b4.w) / dg; qv = (q4.w + b4.w * b4.w) / dg;
      u[3] = (__bf16)sqrtf(fmaxf(qv - sv * sv, 1e-6f));
      *(bf16x4*)&updb[row][4 * k] = u;
    }
  }
  __syncthreads();

  // ---- MFMA epilogue: wave wv -> node-tile wv>>1, col-half wv&1 ----
  int tt = wv >> 1, chh = wv & 1;
  bf16x8 af0 = *(const bf16x8*)&updb[tt * 16 + (ln & 15)][q * 8];
  bf16x8 af1 = *(const bf16x8*)&updb[tt * 16 + (ln & 15)][32 + q * 8];
  #pragma unroll
  for (int hh = 0; hh < 2; ++hh) {
    int cc = chh * 32 + hh * 16 + (ln & 15);
    bf16x8 bfr0, bfr1;
    #pragma unroll
    for (int j = 0; j < 8; ++j) {
      bfr0[j] = (__bf16)loadF(W, cc * 64 + q * 8 + j, bfW);
      bfr1[j] = (__bf16)loadF(W, cc * 64 + 32 + q * 8 + j, bfW);
    }
    float bias = loadF(bv, cc, bfW);
    f32x4 accv = {0.f, 0.f, 0.f, 0.f};
    accv = __builtin_amdgcn_mfma_f32_16x16x32_bf16(af0, bfr0, accv, 0, 0, 0);
    accv = __builtin_amdgcn_mfma_f32_16x16x32_bf16(af1, bfr1, accv, 0, 0, 0);
    #pragma unroll
    for (int i = 0; i < 4; ++i) {
      int nn = n0 + tt * 16 + q * 4 + i;
      if (nn < hi) {
        float v = accv[i] + bias;
        if (bfI) ((__hip_bfloat16*)out)[nn * 64 + cc] = __float2bfloat16(v);
        else     ((float*)out)[nn * 64 + cc] = v;
      }
    }
  }
}

extern "C" void kernel_launch(void* const* d_in, const int* in_sizes, int n_in,
                              void* d_out, int out_size, void* d_ws, size_t ws_size,
                              hipStream_t stream) {
  const void* input    = d_in[0];
  const void* boundary = d_in[1];
  const int*  edges    = (const int*)d_in[2];
  const void* eweight  = d_in[3];
  const void* relw     = d_in[4];
  const void* W        = d_in[5];
  const void* bv       = d_in[6];

  int* wsI    = (int*)d_ws;
  int* flags  = wsI + OFF_FLAGS;
  int* boff   = wsI + OFF_BOFF;
  int* bcur   = wsI + OFF_BCUR;

  long avail = (long)(ws_size / 4) - OFF_INP16;
  int useH = (avail >= (long)NE + 1600000 + 16384) ? 1 : 0;
  unsigned short* inph = useH ? (unsigned short*)(wsI + OFF_INP16) : 0;
  unsigned short* rwh  = useH ? (unsigned short*)(wsI + OFF_RELW16) : 0;
  int* eidx = useH ? (wsI + OFF_EIDX_H) : (wsI + OFF_INP16);
  long cap = useH ? (avail - 1600000 - 16384) : avail;
  if (cap < 1) cap = 1;
  int npass;
  if      (cap >= (long)NE) npass = 1;
  else if (cap >= 1000000)  npass = 2;
  else if (cap >= 520000)   npass = 4;
  else                      npass = 8;

  k_detect<<<1, 64, 0, stream>>>(input, boundary, relw, W, eweight,
                                 flags, boff);
  if (useH)
    k_stage<<<(NN * 16 + 255) / 256, 256, 0, stream>>>(input, relw, inph,
                                                       rwh, flags);
  k_bhist<<<(NE + 8191) / 8192, 256, 0, stream>>>(edges, eweight, boff, flags);
  k_scanb<<<1, 256, 0, stream>>>(boff, bcur);

  const int PA_NB = (NE + CHUNK - 1) / CHUNK;
  for (int p = 0; p < npass; ++p) {
    int gb0 = NBK * p / npass;
    int gb1 = NBK * (p + 1) / npass;
    int hi = (gb1 * 128 < NN) ? gb1 * 128 : NN;
    k_parta<<<PA_NB, 256, 0, stream>>>(edges, bcur, eidx, flags, boff,
                                       gb0, gb1, (int)cap);
    k_node<<<gb1 - gb0, 1024, 0, stream>>>(
        input, boundary, edges, eweight, relw, W, bv, boff, eidx, flags,
        inph, rwh, d_out, gb0, hi, (int)cap);
  }
}

// Round 8
// 238.988 us; speedup vs baseline: 6.3728x; 1.0087x over previous
//
#include <hip/hip_runtime.h>
#include <hip/hip_bf16.h>
#include <hip/hip_fp16.h>

#define NN  50000
#define NE  1600000
#define DIM 64
#define NBK 391          // 128-node buckets

// ---- ws layout (int32 offsets) -------------------------------------------
#define OFF_FLAGS  0            // 8 ints
#define OFF_BOFF   8            // 392 compact exclusive offsets
#define OFF_BCNTP  400          // 391*16 padded counts (64B/bucket: atomics)
#define OFF_BCURP  8000         // 391*16 padded cursors (64B/bucket: atomics)
#define OFF_INP16  50800        // fp16 input stage (1.6M ints) when useH
#define OFF_RELW16 1650800      // fp16 relw stage (16384 ints) when useH
#define OFF_EIDX_H 1667184      // eidx when staged
// eidx at 50800 when not staged

#define CHUNK 4096   // edges per k_parta block
#define SBCAP 7936   // in-LDS sort capacity (expected bucket ~4092)

typedef __bf16 bf16x8 __attribute__((ext_vector_type(8)));
typedef __bf16 bf16x4 __attribute__((ext_vector_type(4)));
typedef float  f32x4  __attribute__((ext_vector_type(4)));

__device__ __forceinline__ float loadF(const void* p, int i, int bf) {
  if (bf) return __bfloat162float(((const __hip_bfloat16*)p)[i]);
  return ((const float*)p)[i];
}

__device__ __forceinline__ float4 loadF4(const void* p, int i4, int bf) {
  if (bf) {
    ushort4 u = ((const ushort4*)p)[i4];
    float4 f;
    union { unsigned int ui; float fl; } c;
    c.ui = (unsigned int)u.x << 16; f.x = c.fl;
    c.ui = (unsigned int)u.y << 16; f.y = c.fl;
    c.ui = (unsigned int)u.z << 16; f.z = c.fl;
    c.ui = (unsigned int)u.w << 16; f.w = c.fl;
    return f;
  }
  return ((const float4*)p)[i4];
}

__device__ __forceinline__ float4 h4f(ushort4 u) {
  float4 f;
  f.x = __half2float(__ushort_as_half(u.x));
  f.y = __half2float(__ushort_as_half(u.y));
  f.z = __half2float(__ushort_as_half(u.z));
  f.w = __half2float(__ushort_as_half(u.w));
  return f;
}

__device__ __forceinline__ void accum(ushort4 ua, ushort4 ur,
                                      float4& s4, float4& q4) {
  float4 a = h4f(ua), r = h4f(ur);
  float tx = a.x * r.x, ty = a.y * r.y, tz = a.z * r.z, tw = a.w * r.w;
  s4.x += tx; q4.x = fmaf(tx, tx, q4.x);
  s4.y += ty; q4.y = fmaf(ty, ty, q4.y);
  s4.z += tz; q4.z = fmaf(tz, tz, q4.z);
  s4.w += tw; q4.w = fmaf(tw, tw, q4.w);
}

// Per-array dtype detection + zero padded bucket counts.
__global__ void k_detect(const void* input, const void* boundary,
                         const void* relw, const void* W, const void* ew,
                         int* flags, int* bcntp) {
  __shared__ int cnt;
  int t = threadIdx.x;  // 64 threads
  const void* arrs[4] = {input, boundary, relw, W};
  for (int a = 0; a < 4; ++a) {
    if (t == 0) cnt = 0;
    __syncthreads();
    const unsigned short* u = (const unsigned short*)arrs[a];
    unsigned ex = (u[2 * t] >> 7) & 0xFF;
    if (ex >= 100 && ex <= 140) atomicAdd(&cnt, 1);
    __syncthreads();
    if (t == 0) flags[a] = (cnt >= 32) ? 1 : 0;
    __syncthreads();
  }
  if (t == 0) {
    flags[4] = (((const unsigned short*)ew)[0] == 0x3F80) ? 1 : 0;
    flags[5] = 1;
  }
  for (int i = t; i < NBK * 16; i += 64) bcntp[i] = 0;
}

// Stage input + relw as fp16 (only when both are f32; hot path needs that).
__global__ __launch_bounds__(256) void k_stage(const void* __restrict__ in,
                                               const void* __restrict__ rw,
                                               unsigned short* __restrict__ inph,
                                               unsigned short* __restrict__ rwh,
                                               const int* __restrict__ flags) {
  if (flags[0] || flags[2]) return;   // non-f32 input/relw: hot path disabled
  int i = blockIdx.x * 256 + threadIdx.x;
  if (i < NN * 16) {
    float4 v = ((const float4*)in)[i];
    ushort4 h;
    h.x = __half_as_ushort(__float2half(v.x));
    h.y = __half_as_ushort(__float2half(v.y));
    h.z = __half_as_ushort(__float2half(v.z));
    h.w = __half_as_ushort(__float2half(v.w));
    ((ushort4*)inph)[i] = h;
  }
  if (i < 512 * 16) {
    float4 v = ((const float4*)rw)[i];
    ushort4 h;
    h.x = __half_as_ushort(__float2half(v.x));
    h.y = __half_as_ushort(__float2half(v.y));
    h.z = __half_as_ushort(__float2half(v.z));
    h.w = __half_as_ushort(__float2half(v.w));
    ((ushort4*)rwh)[i] = h;
  }
}

// Bucket-level histogram (LDS-privatized) + exact all-ones check of ew.
// Global accumulation hits padded bcntp[b*16]: one cacheline per bucket.
__global__ __launch_bounds__(256) void k_bhist(const int* __restrict__ el,
                                               const void* __restrict__ ew,
                                               int* __restrict__ bcntp,
                                               int* __restrict__ flags) {
  __shared__ int lc[NBK];
  int t = threadIdx.x;
  int bfE = flags[4];
  for (int i = t; i < NBK; i += 256) lc[i] = 0;
  __syncthreads();
  int c0 = blockIdx.x * 8192;
  int bad = 0;
  for (int i = t; i < 8192; i += 256) {
    int e = c0 + i;
    if (e < NE) {
      atomicAdd(&lc[el[e * 3 + 1] >> 7], 1);
      if (loadF(ew, e, bfE) != 1.0f) bad = 1;
    }
  }
  if (bad) flags[5] = 0;
  __syncthreads();
  for (int i = t; i < NBK; i += 256)
    if (lc[i]) atomicAdd(&bcntp[i * 16], lc[i]);
}

// Exclusive scan of padded counts -> compact boff + padded cursors.
__global__ __launch_bounds__(256) void k_scanb(const int* __restrict__ bcntp,
                                               int* __restrict__ boff,
                                               int* __restrict__ bcurp) {
  __shared__ int sc[256];
  int t = threadIdx.x;
  int i0 = 2 * t, i1 = 2 * t + 1;
  int a = (i0 < NBK) ? bcntp[i0 * 16] : 0;
  int b = (i1 < NBK) ? bcntp[i1 * 16] : 0;
  sc[t] = a + b;
  __syncthreads();
  for (int off = 1; off < 256; off <<= 1) {
    int v = (t >= off) ? sc[t - off] : 0;
    __syncthreads();
    sc[t] += v;
    __syncthreads();
  }
  int excl = sc[t] - (a + b);
  if (i0 < 392) boff[i0] = excl;
  if (i1 < 392) boff[i1] = excl + a;
  if (i0 < NBK) bcurp[i0 * 16] = excl;
  if (i1 < NBK) bcurp[i1 * 16] = excl + a;
}

// Partition edges into per-bucket regions via LDS staging (contiguous runs).
// rec = nin|rel<<16|local<<25 (ones) or e|local<<25 (generic).
// Cursor atomics hit padded bcurp[b*16]: one cacheline per bucket.
__global__ __launch_bounds__(256) void k_parta(
    const int* __restrict__ el, int* __restrict__ bcurp,
    int* __restrict__ eidx, const int* __restrict__ flags,
    const int* __restrict__ boff, int gb0, int gb1, int cap) {
  __shared__ int stage[CHUNK];
  __shared__ unsigned short sbk[CHUNK];
  __shared__ int lh[NBK], lbase[NBK], lh2[NBK], gbs[NBK];
  __shared__ int sc[256];
  __shared__ int total;
  int t = threadIdx.x;
  int nb = gb1 - gb0;
  int c0 = blockIdx.x * CHUNK;
  int ones = flags[5];
  int base0 = boff[gb0];
  for (int i = t; i < nb; i += 256) { lh[i] = 0; lh2[i] = 0; }
  __syncthreads();
  for (int i = t; i < CHUNK; i += 256) {
    int e = c0 + i;
    if (e < NE) {
      int b = (el[e * 3 + 1] >> 7) - gb0;
      if (b >= 0 && b < nb) atomicAdd(&lh[b], 1);
    }
  }
  __syncthreads();
  int a0 = (2 * t < nb) ? lh[2 * t] : 0;
  int a1 = (2 * t + 1 < nb) ? lh[2 * t + 1] : 0;
  sc[t] = a0 + a1;
  __syncthreads();
  for (int off = 1; off < 256; off <<= 1) {
    int v = (t >= off) ? sc[t - off] : 0;
    __syncthreads();
    sc[t] += v;
    __syncthreads();
  }
  int excl = sc[t] - (a0 + a1);
  if (2 * t < nb) {
    lbase[2 * t] = excl;
    if (a0 > 0) gbs[2 * t] = atomicAdd(&bcurp[(gb0 + 2 * t) * 16], a0);
  }
  if (2 * t + 1 < nb) {
    lbase[2 * t + 1] = excl + a0;
    if (a1 > 0) gbs[2 * t + 1] = atomicAdd(&bcurp[(gb0 + 2 * t + 1) * 16], a1);
  }
  if (t == 255) total = sc[255];
  __syncthreads();
  for (int i = t; i < CHUNK; i += 256) {
    int e = c0 + i;
    if (e < NE) {
      int nout = el[e * 3 + 1];
      int b = (nout >> 7) - gb0;
      if (b >= 0 && b < nb) {
        int r = atomicAdd(&lh2[b], 1);
        int slot = lbase[b] + r;
        int rec = ones ? (el[e * 3] | (el[e * 3 + 2] << 16) |
                          ((nout & 127) << 25))
                       : (e | ((nout & 127) << 25));
        stage[slot] = rec;
        sbk[slot] = (unsigned short)b;
      }
    }
  }
  __syncthreads();
  int tot = total;
  for (int i = t; i < tot; i += 256) {
    int b = sbk[i];
    int dst = gbs[b] + (i - lbase[b]) - base0;
    if (dst >= 0 && dst < cap) eidx[dst] = stage[i];
  }
}

// Fused sort+node kernel (R7, 241us verified). One 1024-thread block = one
// 128-node bucket; in-LDS counting sort (ld -> ld2), then the proven edge
// phase reading sorted records from LDS. eidx read once.
__global__ __launch_bounds__(1024, 8) void k_node(
    const void* __restrict__ input, const void* __restrict__ boundary,
    const int* __restrict__ el, const void* __restrict__ ew,
    const void* __restrict__ relw, const void* __restrict__ W,
    const void* __restrict__ bv, const int* __restrict__ boff,
    const int* __restrict__ eidx, const int* __restrict__ flags,
    const unsigned short* __restrict__ inph,
    const unsigned short* __restrict__ rwh,
    void* __restrict__ out, int gb0, int hi, int cap) {
  __shared__ int ld[SBCAP];     // raw records; aliased as updb after scatter
  __shared__ int ld2[SBCAP];    // node-sorted records
  __shared__ int lstart[128], lend[128], lcnt[128];
  __bf16 (*updb)[72] = reinterpret_cast<__bf16(*)[72]>(ld);

  int bfI = flags[0], bfB = flags[1], bfR = flags[2], bfW = flags[3],
      bfE = flags[4], ones = flags[5];
  int t = threadIdx.x;
  int wv = t >> 6, ln = t & 63;
  int g = ln >> 4;           // edge sub-slot group
  int k = ln & 15;           // float4 index within the 64-dim row
  int q = ln >> 4;
  int B = gb0 + blockIdx.x;
  int n0 = B * 128;
  int base0 = boff[gb0];
  int rbase = boff[B], rend = boff[B + 1];
  int cnt = rend - rbase;
  int fast = (cnt <= SBCAP) && (rend - base0 <= cap);

  if (t < 128) lcnt[t] = 0;
  __syncthreads();
  if (fast) {
    for (int i = t; i < cnt; i += 1024) ld[i] = eidx[rbase - base0 + i];
    __syncthreads();
    for (int i = t; i < cnt; i += 1024)
      atomicAdd(&lcnt[(((unsigned)ld[i]) >> 25) & 127], 1);
  }
  __syncthreads();
  // inclusive scan of lcnt in lend
  if (t < 128) lend[t] = lcnt[t];
  __syncthreads();
  for (int off = 1; off < 128; off <<= 1) {
    int v = 0;
    if (t < 128 && t >= off) v = lend[t - off];
    __syncthreads();
    if (t < 128) lend[t] += v;
    __syncthreads();
  }
  if (t < 128) { lstart[t] = lend[t] - lcnt[t]; lcnt[t] = 0; }
  __syncthreads();
  if (fast) {
    for (int i = t; i < cnt; i += 1024) {
      int rec = ld[i];
      int l = (((unsigned)rec) >> 25) & 127;
      int r = atomicAdd(&lcnt[l], 1);
      ld2[lstart[l] + r] = rec;
    }
  }
  __syncthreads();   // ld dead from here -> safe to alias as updb

  const ushort4* ih4 = (const ushort4*)inph;
  const ushort4* rh4 = (const ushort4*)rwh;
  int hot = (!bfI && !bfR && ones && inph != 0) ? 1 : 0;

  // ---- edge phase: 8 nodes per wave ----
  for (int rr = 0; rr < 8; ++rr) {
    int row = wv * 8 + rr;
    int n = n0 + row;
    if (n >= hi) {
      if (g == 0) *(bf16x4*)&updb[row][4 * k] =
          bf16x4{(__bf16)0.f, (__bf16)0.f, (__bf16)0.f, (__bf16)0.f};
      continue;
    }
    float4 s4 = {0.f,0.f,0.f,0.f}, q4 = {0.f,0.f,0.f,0.f};
    float degf = 0.f;
    if (fast) {
      int start = lstart[row], end = lend[row];
      degf = (float)(end - start);
      if (hot) {
        for (int base = start; base < end; base += 64) {
          int mm = end - base; if (mm > 64) mm = 64;
          int rec = 0;
          if (ln < mm) rec = ld2[base + ln];
          int jq = mm >> 2;
          int jmax = (mm + 3) >> 2;
          int j = 0;
          for (; j + 4 <= jq; j += 4) {   // 16 edges per iter
            int pk0 = __shfl(rec, j * 4 + g);
            int pk1 = __shfl(rec, j * 4 + 4 + g);
            int pk2 = __shfl(rec, j * 4 + 8 + g);
            int pk3 = __shfl(rec, j * 4 + 12 + g);
            ushort4 a0 = ih4[(pk0 & 0xFFFF) * 16 + k];
            ushort4 r0 = rh4[((pk0 >> 16) & 0x1FF) * 16 + k];
            ushort4 a1 = ih4[(pk1 & 0xFFFF) * 16 + k];
            ushort4 r1 = rh4[((pk1 >> 16) & 0x1FF) * 16 + k];
            ushort4 a2 = ih4[(pk2 & 0xFFFF) * 16 + k];
            ushort4 r2 = rh4[((pk2 >> 16) & 0x1FF) * 16 + k];
            ushort4 a3 = ih4[(pk3 & 0xFFFF) * 16 + k];
            ushort4 r3 = rh4[((pk3 >> 16) & 0x1FF) * 16 + k];
            accum(a0, r0, s4, q4);
            accum(a1, r1, s4, q4);
            accum(a2, r2, s4, q4);
            accum(a3, r3, s4, q4);
          }
          for (; j < jq; ++j) {
            int pk = __shfl(rec, j * 4 + g);
            ushort4 a = ih4[(pk & 0xFFFF) * 16 + k];
            ushort4 r = rh4[((pk >> 16) & 0x1FF) * 16 + k];
            accum(a, r, s4, q4);
          }
          for (; j < jmax; ++j) {      // predicated tail (<=1 iter)
            int slot = j * 4 + g;
            int pk = __shfl(rec, slot & 63);
            float wsel = (slot < mm) ? 1.0f : 0.0f;
            ushort4 ua = ih4[(pk & 0xFFFF) * 16 + k];
            ushort4 ur = rh4[((pk >> 16) & 0x1FF) * 16 + k];
            float4 a = h4f(ua), r = h4f(ur);
            float tx = a.x*r.x, ty = a.y*r.y, tz = a.z*r.z, tw = a.w*r.w;
            s4.x = fmaf(wsel, tx, s4.x); q4.x = fmaf(wsel*tx, tx, q4.x);
            s4.y = fmaf(wsel, ty, s4.y); q4.y = fmaf(wsel*ty, ty, q4.y);
            s4.z = fmaf(wsel, tz, s4.z); q4.z = fmaf(wsel*tz, tz, q4.z);
            s4.w = fmaf(wsel, tw, s4.w); q4.w = fmaf(wsel*tw, tw, q4.w);
          }
        }
      } else {
        for (int base = start; base < end; base += 64) {
          int mm = end - base; if (mm > 64) mm = 64;
          int rec = 0; float wrec = 0.0f;
          if (ln < mm) {
            rec = ld2[base + ln] & 0x1FFFFFF;
            if (!ones) wrec = loadF(ew, rec, bfE);
          }
          int jmax = (mm + 3) >> 2;
          for (int j = 0; j < jmax; ++j) {
            int slot = j * 4 + g;
            int rj = __shfl(rec, slot);
            int nin, rl; float wj;
            if (ones) { nin = rj & 0xFFFF; rl = (rj >> 16) & 0x1FF; wj = 1.0f; }
            else      { nin = el[rj * 3]; rl = el[rj * 3 + 2];
                        wj = __shfl(wrec, slot); }
            float wsel = (slot < mm) ? wj : 0.0f;
            float4 a = loadF4(input, nin * 16 + k, bfI);
            float4 r = loadF4(relw, rl * 16 + k, bfR);
            float tx = a.x*r.x, ty = a.y*r.y, tz = a.z*r.z, tw = a.w*r.w;
            s4.x = fmaf(wsel, tx, s4.x); q4.x = fmaf(wsel*tx, tx, q4.x);
            s4.y = fmaf(wsel, ty, s4.y); q4.y = fmaf(wsel*ty, ty, q4.y);
            s4.z = fmaf(wsel, tz, s4.z); q4.z = fmaf(wsel*tz, tz, q4.z);
            s4.w = fmaf(wsel, tw, s4.w); q4.w = fmaf(wsel*tw, tw, q4.w);
          }
        }
      }
    } else {
      // correctness-only fallback: scan full edge list for this node
      float degc = 0.f;
      for (int e0 = g; e0 < NE; e0 += 4) {
        int nout = el[e0 * 3 + 1];
        if (nout != n) continue;
        degc += 1.0f;
        int nin = el[e0 * 3], rl = el[e0 * 3 + 2];
        float wj = ones ? 1.0f : loadF(ew, e0, bfE);
        float4 a = loadF4(input, nin * 16 + k, bfI);
        float4 r = loadF4(relw, rl * 16 + k, bfR);
        float tx = wj*a.x*r.x, ty = wj*a.y*r.y, tz = wj*a.z*r.z,
              tw = wj*a.w*r.w;
        s4.x += tx; q4.x = fmaf(tx, tx, q4.x);
        s4.y += ty; q4.y = fmaf(ty, ty, q4.y);
        s4.z += tz; q4.z = fmaf(tz, tz, q4.z);
        s4.w += tw; q4.w = fmaf(tw, tw, q4.w);
      }
      degc += __shfl_xor(degc, 16); degc += __shfl_xor(degc, 32);
      degf = degc;
    }
    s4.x += __shfl_xor(s4.x, 16); s4.x += __shfl_xor(s4.x, 32);
    s4.y += __shfl_xor(s4.y, 16); s4.y += __shfl_xor(s4.y, 32);
    s4.z += __shfl_xor(s4.z, 16); s4.z += __shfl_xor(s4.z, 32);
    s4.w += __shfl_xor(s4.w, 16); s4.w += __shfl_xor(s4.w, 32);
    q4.x += __shfl_xor(q4.x, 16); q4.x += __shfl_xor(q4.x, 32);
    q4.y += __shfl_xor(q4.y, 16); q4.y += __shfl_xor(q4.y, 32);
    q4.z += __shfl_xor(q4.z, 16); q4.z += __shfl_xor(q4.z, 32);
    q4.w += __shfl_xor(q4.w, 16); q4.w += __shfl_xor(q4.w, 32);
    if (g == 0) {
      float4 b4 = loadF4(boundary, n * 16 + k, bfB);
      float dg = degf + 1.0f;
      float sv, qv;
      bf16x4 u;
      sv = (s4.x + b4.x) / dg; qv = (q4.x + b4.x * b4.x) / dg;
      u[0] = (__bf16)sqrtf(fmaxf(qv - sv * sv, 1e-6f));
      sv = (s4.y + b4.y) / dg; qv = (q4.y + b4.y * b4.y) / dg;
      u[1] = (__bf16)sqrtf(fmaxf(qv - sv * sv, 1e-6f));
      sv = (s4.z + b4.z) / dg; qv = (q4.z + b4.z * b4.z) / dg;
      u[2] = (__bf16)sqrtf(fmaxf(qv - sv * sv, 1e-6f));
      sv = (s4.w + b4.w) / dg; qv = (q4.w + b4.w * b4.w) / dg;
      u[3] = (__bf16)sqrtf(fmaxf(qv - sv * sv, 1e-6f));
      *(bf16x4*)&updb[row][4 * k] = u;
    }
  }
  __syncthreads();

  // ---- MFMA epilogue: wave wv -> node-tile wv>>1, col-half wv&1 ----
  int tt = wv >> 1, chh = wv & 1;
  bf16x8 af0 = *(const bf16x8*)&updb[tt * 16 + (ln & 15)][q * 8];
  bf16x8 af1 = *(const bf16x8*)&updb[tt * 16 + (ln & 15)][32 + q * 8];
  #pragma unroll
  for (int hh = 0; hh < 2; ++hh) {
    int cc = chh * 32 + hh * 16 + (ln & 15);
    bf16x8 bfr0, bfr1;
    #pragma unroll
    for (int j = 0; j < 8; ++j) {
      bfr0[j] = (__bf16)loadF(W, cc * 64 + q * 8 + j, bfW);
      bfr1[j] = (__bf16)loadF(W, cc * 64 + 32 + q * 8 + j, bfW);
    }
    float bias = loadF(bv, cc, bfW);
    f32x4 accv = {0.f, 0.f, 0.f, 0.f};
    accv = __builtin_amdgcn_mfma_f32_16x16x32_bf16(af0, bfr0, accv, 0, 0, 0);
    accv = __builtin_amdgcn_mfma_f32_16x16x32_bf16(af1, bfr1, accv, 0, 0, 0);
    #pragma unroll
    for (int i = 0; i < 4; ++i) {
      int nn = n0 + tt * 16 + q * 4 + i;
      if (nn < hi) {
        float v = accv[i] + bias;
        if (bfI) ((__hip_bfloat16*)out)[nn * 64 + cc] = __float2bfloat16(v);
        else     ((float*)out)[nn * 64 + cc] = v;
      }
    }
  }
}

extern "C" void kernel_launch(void* const* d_in, const int* in_sizes, int n_in,
                              void* d_out, int out_size, void* d_ws, size_t ws_size,
                              hipStream_t stream) {
  const void* input    = d_in[0];
  const void* boundary = d_in[1];
  const int*  edges    = (const int*)d_in[2];
  const void* eweight  = d_in[3];
  const void* relw     = d_in[4];
  const void* W        = d_in[5];
  const void* bv       = d_in[6];

  int* wsI    = (int*)d_ws;
  int* flags  = wsI + OFF_FLAGS;
  int* boff   = wsI + OFF_BOFF;
  int* bcntp  = wsI + OFF_BCNTP;
  int* bcurp  = wsI + OFF_BCURP;

  long avail = (long)(ws_size / 4) - OFF_INP16;
  int useH = (avail >= (long)NE + 1600000 + 16384) ? 1 : 0;
  unsigned short* inph = useH ? (unsigned short*)(wsI + OFF_INP16) : 0;
  unsigned short* rwh  = useH ? (unsigned short*)(wsI + OFF_RELW16) : 0;
  int* eidx = useH ? (wsI + OFF_EIDX_H) : (wsI + OFF_INP16);
  long cap = useH ? (avail - 1600000 - 16384) : avail;
  if (cap < 1) cap = 1;
  int npass;
  if      (cap >= (long)NE) npass = 1;
  else if (cap >= 1000000)  npass = 2;
  else if (cap >= 520000)   npass = 4;
  else                      npass = 8;

  k_detect<<<1, 64, 0, stream>>>(input, boundary, relw, W, eweight,
                                 flags, bcntp);
  if (useH)
    k_stage<<<(NN * 16 + 255) / 256, 256, 0, stream>>>(input, relw, inph,
                                                       rwh, flags);
  k_bhist<<<(NE + 8191) / 8192, 256, 0, stream>>>(edges, eweight, bcntp,
                                                  flags);
  k_scanb<<<1, 256, 0, stream>>>(bcntp, boff, bcurp);

  const int PA_NB = (NE + CHUNK - 1) / CHUNK;
  for (int p = 0; p < npass; ++p) {
    int gb0 = NBK * p / npass;
    int gb1 = NBK * (p + 1) / npass;
    int hi = (gb1 * 128 < NN) ? gb1 * 128 : NN;
    k_parta<<<PA_NB, 256, 0, stream>>>(edges, bcurp, eidx, flags, boff,
                                       gb0, gb1, (int)cap);
    k_node<<<gb1 - gb0, 1024, 0, stream>>>(
        input, boundary, edges, eweight, relw, W, bv, boff, eidx, flags,
        inph, rwh, d_out, gb0, hi, (int)cap);
  }
}

// Round 9
// 224.593 us; speedup vs baseline: 6.7813x; 1.0641x over previous
//
#include <hip/hip_runtime.h>
#include <hip/hip_bf16.h>

#define NN  50000
#define NE  1600000
#define DIM 64
#define NBK 391          // 128-node buckets

// ---- ws layout (int32 offsets) -------------------------------------------
#define OFF_FLAGS  0            // 8 ints
#define OFF_BCURP  8            // 391*16 padded cursors (64B/bucket, atomics)
#define OFF_EIDX   6272         // padded records: [bucket][PADCAP]

#define CHUNK 4096   // edges per k_parta block
#define SBCAP 7936   // in-LDS sort capacity (expected max bucket ~4400)

typedef __bf16 bf16x8 __attribute__((ext_vector_type(8)));
typedef __bf16 bf16x4 __attribute__((ext_vector_type(4)));
typedef float  f32x4  __attribute__((ext_vector_type(4)));

__device__ __forceinline__ float loadF(const void* p, int i, int bf) {
  if (bf) return __bfloat162float(((const __hip_bfloat16*)p)[i]);
  return ((const float*)p)[i];
}

__device__ __forceinline__ float4 loadF4(const void* p, int i4, int bf) {
  if (bf) {
    ushort4 u = ((const ushort4*)p)[i4];
    float4 f;
    union { unsigned int ui; float fl; } c;
    c.ui = (unsigned int)u.x << 16; f.x = c.fl;
    c.ui = (unsigned int)u.y << 16; f.y = c.fl;
    c.ui = (unsigned int)u.z << 16; f.z = c.fl;
    c.ui = (unsigned int)u.w << 16; f.w = c.fl;
    return f;
  }
  return ((const float4*)p)[i4];
}

__device__ __forceinline__ void accumF(float4 a, float4 r,
                                       float4& s4, float4& q4) {
  float tx = a.x * r.x, ty = a.y * r.y, tz = a.z * r.z, tw = a.w * r.w;
  s4.x += tx; q4.x = fmaf(tx, tx, q4.x);
  s4.y += ty; q4.y = fmaf(ty, ty, q4.y);
  s4.z += tz; q4.z = fmaf(tz, tz, q4.z);
  s4.w += tw; q4.w = fmaf(tw, tw, q4.w);
}

// Per-array dtype detection + zero padded bucket cursors.
__global__ void k_detect(const void* input, const void* boundary,
                         const void* relw, const void* W, const void* ew,
                         int* flags, int* bcurp) {
  __shared__ int cnt;
  int t = threadIdx.x;  // 64 threads
  const void* arrs[4] = {input, boundary, relw, W};
  for (int a = 0; a < 4; ++a) {
    if (t == 0) cnt = 0;
    __syncthreads();
    const unsigned short* u = (const unsigned short*)arrs[a];
    unsigned ex = (u[2 * t] >> 7) & 0xFF;
    if (ex >= 100 && ex <= 140) atomicAdd(&cnt, 1);
    __syncthreads();
    if (t == 0) flags[a] = (cnt >= 32) ? 1 : 0;
    __syncthreads();
  }
  if (t == 0) {
    flags[4] = (((const unsigned short*)ew)[0] == 0x3F80) ? 1 : 0;
    flags[5] = 1;
  }
  for (int i = t; i < NBK * 16; i += 64) bcurp[i] = 0;
}

// Exact all-ones check of edge weights.
__global__ __launch_bounds__(256) void k_ew(const void* __restrict__ ew,
                                            int* __restrict__ flags) {
  int bfE = flags[4];
  int c0 = blockIdx.x * 8192;
  int bad = 0;
  for (int i = threadIdx.x; i < 8192; i += 256) {
    int e = c0 + i;
    if (e < NE && loadF(ew, e, bfE) != 1.0f) bad = 1;
  }
  if (bad) flags[5] = 0;
}

// Partition edges into PADDED per-bucket regions via LDS staging.
// No prior histogram needed: region base is b*PADCAP, slot via one
// atomicAdd per (block,bucket). rec = nin|rel<<16|local<<25 (ones)
// or e|local<<25 (generic).
__global__ __launch_bounds__(256) void k_parta(
    const int* __restrict__ el, int* __restrict__ bcurp,
    int* __restrict__ eidx, const int* __restrict__ flags,
    int gb0, int gb1, int padcap) {
  __shared__ int stage[CHUNK];
  __shared__ unsigned short sbk[CHUNK];
  __shared__ int lh[NBK], lbase[NBK], lh2[NBK], gbs[NBK];
  __shared__ int sc[256];
  __shared__ int total;
  int t = threadIdx.x;
  int nb = gb1 - gb0;
  int c0 = blockIdx.x * CHUNK;
  int ones = flags[5];
  for (int i = t; i < nb; i += 256) { lh[i] = 0; lh2[i] = 0; }
  __syncthreads();
  for (int i = t; i < CHUNK; i += 256) {
    int e = c0 + i;
    if (e < NE) {
      int b = (el[e * 3 + 1] >> 7) - gb0;
      if (b >= 0 && b < nb) atomicAdd(&lh[b], 1);
    }
  }
  __syncthreads();
  int a0 = (2 * t < nb) ? lh[2 * t] : 0;
  int a1 = (2 * t + 1 < nb) ? lh[2 * t + 1] : 0;
  sc[t] = a0 + a1;
  __syncthreads();
  for (int off = 1; off < 256; off <<= 1) {
    int v = (t >= off) ? sc[t - off] : 0;
    __syncthreads();
    sc[t] += v;
    __syncthreads();
  }
  int excl = sc[t] - (a0 + a1);
  if (2 * t < nb) {
    lbase[2 * t] = excl;
    if (a0 > 0) gbs[2 * t] = atomicAdd(&bcurp[(gb0 + 2 * t) * 16], a0);
  }
  if (2 * t + 1 < nb) {
    lbase[2 * t + 1] = excl + a0;
    if (a1 > 0) gbs[2 * t + 1] = atomicAdd(&bcurp[(gb0 + 2 * t + 1) * 16], a1);
  }
  if (t == 255) total = sc[255];
  __syncthreads();
  for (int i = t; i < CHUNK; i += 256) {
    int e = c0 + i;
    if (e < NE) {
      int nout = el[e * 3 + 1];
      int b = (nout >> 7) - gb0;
      if (b >= 0 && b < nb) {
        int r = atomicAdd(&lh2[b], 1);
        int slot = lbase[b] + r;
        int rec = ones ? (el[e * 3] | (el[e * 3 + 2] << 16) |
                          ((nout & 127) << 25))
                       : (e | ((nout & 127) << 25));
        stage[slot] = rec;
        sbk[slot] = (unsigned short)b;
      }
    }
  }
  __syncthreads();
  int tot = total;
  for (int i = t; i < tot; i += 256) {
    int b = sbk[i];
    int slot = gbs[b] + (i - lbase[b]);
    if (slot < padcap) eidx[(long)b * padcap + slot] = stage[i];
  }
}

// Fused sort+node kernel (R7/R8 structure, 96us verified). One 1024-thread
// block = one 128-node bucket; in-LDS counting sort (ld -> ld2), then the
// proven edge phase (f32 gathers: R3 showed fp16 staging was time-neutral).
__global__ __launch_bounds__(1024, 8) void k_node(
    const void* __restrict__ input, const void* __restrict__ boundary,
    const int* __restrict__ el, const void* __restrict__ ew,
    const void* __restrict__ relw, const void* __restrict__ W,
    const void* __restrict__ bv, const int* __restrict__ bcurp,
    const int* __restrict__ eidx, const int* __restrict__ flags,
    void* __restrict__ out, int gb0, int hi, int padcap) {
  __shared__ int ld[SBCAP];     // raw records; aliased as updb after scatter
  __shared__ int ld2[SBCAP];    // node-sorted records
  __shared__ int lstart[128], lend[128], lcnt[128];
  __bf16 (*updb)[72] = reinterpret_cast<__bf16(*)[72]>(ld);

  int bfI = flags[0], bfB = flags[1], bfR = flags[2], bfW = flags[3],
      bfE = flags[4], ones = flags[5];
  int t = threadIdx.x;
  int wv = t >> 6, ln = t & 63;
  int g = ln >> 4;           // edge sub-slot group
  int k = ln & 15;           // float4 index within the 64-dim row
  int q = ln >> 4;
  int B = gb0 + blockIdx.x;
  int n0 = B * 128;
  int cnt = bcurp[B * 16];
  int fast = (cnt <= SBCAP) && (cnt <= padcap);
  const int* myeidx = eidx + (long)blockIdx.x * padcap;

  if (t < 128) lcnt[t] = 0;
  __syncthreads();
  if (fast) {
    for (int i = t; i < cnt; i += 1024) ld[i] = myeidx[i];
    __syncthreads();
    for (int i = t; i < cnt; i += 1024)
      atomicAdd(&lcnt[(((unsigned)ld[i]) >> 25) & 127], 1);
  }
  __syncthreads();
  // inclusive scan of lcnt in lend
  if (t < 128) lend[t] = lcnt[t];
  __syncthreads();
  for (int off = 1; off < 128; off <<= 1) {
    int v = 0;
    if (t < 128 && t >= off) v = lend[t - off];
    __syncthreads();
    if (t < 128) lend[t] += v;
    __syncthreads();
  }
  if (t < 128) { lstart[t] = lend[t] - lcnt[t]; lcnt[t] = 0; }
  __syncthreads();
  if (fast) {
    for (int i = t; i < cnt; i += 1024) {
      int rec = ld[i];
      int l = (((unsigned)rec) >> 25) & 127;
      int r = atomicAdd(&lcnt[l], 1);
      ld2[lstart[l] + r] = rec;
    }
  }
  __syncthreads();   // ld dead from here -> safe to alias as updb

  const float4* inp4 = (const float4*)input;
  const float4* rw4  = (const float4*)relw;
  int hot = (!bfI && !bfR && ones) ? 1 : 0;

  // ---- edge phase: 8 nodes per wave ----
  for (int rr = 0; rr < 8; ++rr) {
    int row = wv * 8 + rr;
    int n = n0 + row;
    if (n >= hi) {
      if (g == 0) *(bf16x4*)&updb[row][4 * k] =
          bf16x4{(__bf16)0.f, (__bf16)0.f, (__bf16)0.f, (__bf16)0.f};
      continue;
    }
    float4 s4 = {0.f,0.f,0.f,0.f}, q4 = {0.f,0.f,0.f,0.f};
    float degf = 0.f;
    if (fast) {
      int start = lstart[row], end = lend[row];
      degf = (float)(end - start);
      if (hot) {
        for (int base = start; base < end; base += 64) {
          int mm = end - base; if (mm > 64) mm = 64;
          int rec = 0;
          if (ln < mm) rec = ld2[base + ln];
          int jq = mm >> 2;
          int jmax = (mm + 3) >> 2;
          int j = 0;
          for (; j + 4 <= jq; j += 4) {   // 16 edges per iter
            int pk0 = __shfl(rec, j * 4 + g);
            int pk1 = __shfl(rec, j * 4 + 4 + g);
            int pk2 = __shfl(rec, j * 4 + 8 + g);
            int pk3 = __shfl(rec, j * 4 + 12 + g);
            float4 a0 = inp4[(pk0 & 0xFFFF) * 16 + k];
            float4 r0 = rw4[((pk0 >> 16) & 0x1FF) * 16 + k];
            float4 a1 = inp4[(pk1 & 0xFFFF) * 16 + k];
            float4 r1 = rw4[((pk1 >> 16) & 0x1FF) * 16 + k];
            float4 a2 = inp4[(pk2 & 0xFFFF) * 16 + k];
            float4 r2 = rw4[((pk2 >> 16) & 0x1FF) * 16 + k];
            float4 a3 = inp4[(pk3 & 0xFFFF) * 16 + k];
            float4 r3 = rw4[((pk3 >> 16) & 0x1FF) * 16 + k];
            accumF(a0, r0, s4, q4);
            accumF(a1, r1, s4, q4);
            accumF(a2, r2, s4, q4);
            accumF(a3, r3, s4, q4);
          }
          for (; j < jq; ++j) {
            int pk = __shfl(rec, j * 4 + g);
            float4 a = inp4[(pk & 0xFFFF) * 16 + k];
            float4 r = rw4[((pk >> 16) & 0x1FF) * 16 + k];
            accumF(a, r, s4, q4);
          }
          for (; j < jmax; ++j) {      // predicated tail (<=1 iter)
            int slot = j * 4 + g;
            int pk = __shfl(rec, slot & 63);
            float wsel = (slot < mm) ? 1.0f : 0.0f;
            float4 a = inp4[(pk & 0xFFFF) * 16 + k];
            float4 r = rw4[((pk >> 16) & 0x1FF) * 16 + k];
            float tx = a.x*r.x, ty = a.y*r.y, tz = a.z*r.z, tw = a.w*r.w;
            s4.x = fmaf(wsel, tx, s4.x); q4.x = fmaf(wsel*tx, tx, q4.x);
            s4.y = fmaf(wsel, ty, s4.y); q4.y = fmaf(wsel*ty, ty, q4.y);
            s4.z = fmaf(wsel, tz, s4.z); q4.z = fmaf(wsel*tz, tz, q4.z);
            s4.w = fmaf(wsel, tw, s4.w); q4.w = fmaf(wsel*tw, tw, q4.w);
          }
        }
      } else {
        for (int base = start; base < end; base += 64) {
          int mm = end - base; if (mm > 64) mm = 64;
          int rec = 0; float wrec = 0.0f;
          if (ln < mm) {
            rec = ld2[base + ln] & 0x1FFFFFF;
            if (!ones) wrec = loadF(ew, rec, bfE);
          }
          int jmax = (mm + 3) >> 2;
          for (int j = 0; j < jmax; ++j) {
            int slot = j * 4 + g;
            int rj = __shfl(rec, slot);
            int nin, rl; float wj;
            if (ones) { nin = rj & 0xFFFF; rl = (rj >> 16) & 0x1FF; wj = 1.0f; }
            else      { nin = el[rj * 3]; rl = el[rj * 3 + 2];
                        wj = __shfl(wrec, slot); }
            float wsel = (slot < mm) ? wj : 0.0f;
            float4 a = loadF4(input, nin * 16 + k, bfI);
            float4 r = loadF4(relw, rl * 16 + k, bfR);
            float tx = a.x*r.x, ty = a.y*r.y, tz = a.z*r.z, tw = a.w*r.w;
            s4.x = fmaf(wsel, tx, s4.x); q4.x = fmaf(wsel*tx, tx, q4.x);
            s4.y = fmaf(wsel, ty, s4.y); q4.y = fmaf(wsel*ty, ty, q4.y);
            s4.z = fmaf(wsel, tz, s4.z); q4.z = fmaf(wsel*tz, tz, q4.z);
            s4.w = fmaf(wsel, tw, s4.w); q4.w = fmaf(wsel*tw, tw, q4.w);
          }
        }
      }
    } else {
      // correctness-only fallback: scan full edge list for this node
      float degc = 0.f;
      for (int e0 = g; e0 < NE; e0 += 4) {
        int nout = el[e0 * 3 + 1];
        if (nout != n) continue;
        degc += 1.0f;
        int nin = el[e0 * 3], rl = el[e0 * 3 + 2];
        float wj = ones ? 1.0f : loadF(ew, e0, bfE);
        float4 a = loadF4(input, nin * 16 + k, bfI);
        float4 r = loadF4(relw, rl * 16 + k, bfR);
        float tx = wj*a.x*r.x, ty = wj*a.y*r.y, tz = wj*a.z*r.z,
              tw = wj*a.w*r.w;
        s4.x += tx; q4.x = fmaf(tx, tx, q4.x);
        s4.y += ty; q4.y = fmaf(ty, ty, q4.y);
        s4.z += tz; q4.z = fmaf(tz, tz, q4.z);
        s4.w += tw; q4.w = fmaf(tw, tw, q4.w);
      }
      degc += __shfl_xor(degc, 16); degc += __shfl_xor(degc, 32);
      degf = degc;
    }
    s4.x += __shfl_xor(s4.x, 16); s4.x += __shfl_xor(s4.x, 32);
    s4.y += __shfl_xor(s4.y, 16); s4.y += __shfl_xor(s4.y, 32);
    s4.z += __shfl_xor(s4.z, 16); s4.z += __shfl_xor(s4.z, 32);
    s4.w += __shfl_xor(s4.w, 16); s4.w += __shfl_xor(s4.w, 32);
    q4.x += __shfl_xor(q4.x, 16); q4.x += __shfl_xor(q4.x, 32);
    q4.y += __shfl_xor(q4.y, 16); q4.y += __shfl_xor(q4.y, 32);
    q4.z += __shfl_xor(q4.z, 16); q4.z += __shfl_xor(q4.z, 32);
    q4.w += __shfl_xor(q4.w, 16); q4.w += __shfl_xor(q4.w, 32);
    if (g == 0) {
      float4 b4 = loadF4(boundary, n * 16 + k, bfB);
      float dg = degf + 1.0f;
      float sv, qv;
      bf16x4 u;
      sv = (s4.x + b4.x) / dg; qv = (q4.x + b4.x * b4.x) / dg;
      u[0] = (__bf16)sqrtf(fmaxf(qv - sv * sv, 1e-6f));
      sv = (s4.y + b4.y) / dg; qv = (q4.y + b4.y * b4.y) / dg;
      u[1] = (__bf16)sqrtf(fmaxf(qv - sv * sv, 1e-6f));
      sv = (s4.z + b4.z) / dg; qv = (q4.z + b4.z * b4.z) / dg;
      u[2] = (__bf16)sqrtf(fmaxf(qv - sv * sv, 1e-6f));
      sv = (s4.w + b4.w) / dg; qv = (q4.w + b4.w * b4.w) / dg;
      u[3] = (__bf16)sqrtf(fmaxf(qv - sv * sv, 1e-6f));
      *(bf16x4*)&updb[row][4 * k] = u;
    }
  }
  __syncthreads();

  // ---- MFMA epilogue: wave wv -> node-tile wv>>1, col-half wv&1 ----
  int tt = wv >> 1, chh = wv & 1;
  bf16x8 af0 = *(const bf16x8*)&updb[tt * 16 + (ln & 15)][q * 8];
  bf16x8 af1 = *(const bf16x8*)&updb[tt * 16 + (ln & 15)][32 + q * 8];
  #pragma unroll
  for (int hh = 0; hh < 2; ++hh) {
    int cc = chh * 32 + hh * 16 + (ln & 15);
    bf16x8 bfr0, bfr1;
    #pragma unroll
    for (int j = 0; j < 8; ++j) {
      bfr0[j] = (__bf16)loadF(W, cc * 64 + q * 8 + j, bfW);
      bfr1[j] = (__bf16)loadF(W, cc * 64 + 32 + q * 8 + j, bfW);
    }
    float bias = loadF(bv, cc, bfW);
    f32x4 accv = {0.f, 0.f, 0.f, 0.f};
    accv = __builtin_amdgcn_mfma_f32_16x16x32_bf16(af0, bfr0, accv, 0, 0, 0);
    accv = __builtin_amdgcn_mfma_f32_16x16x32_bf16(af1, bfr1, accv, 0, 0, 0);
    #pragma unroll
    for (int i = 0; i < 4; ++i) {
      int nn = n0 + tt * 16 + q * 4 + i;
      if (nn < hi) {
        float v = accv[i] + bias;
        if (bfI) ((__hip_bfloat16*)out)[nn * 64 + cc] = __float2bfloat16(v);
        else     ((float*)out)[nn * 64 + cc] = v;
      }
    }
  }
}

extern "C" void kernel_launch(void* const* d_in, const int* in_sizes, int n_in,
                              void* d_out, int out_size, void* d_ws, size_t ws_size,
                              hipStream_t stream) {
  const void* input    = d_in[0];
  const void* boundary = d_in[1];
  const int*  edges    = (const int*)d_in[2];
  const void* eweight  = d_in[3];
  const void* relw     = d_in[4];
  const void* W        = d_in[5];
  const void* bv       = d_in[6];

  int* wsI    = (int*)d_ws;
  int* flags  = wsI + OFF_FLAGS;
  int* bcurp  = wsI + OFF_BCURP;
  int* eidx   = wsI + OFF_EIDX;

  long avail = (long)(ws_size / 4) - OFF_EIDX;
  if (avail < 1) avail = 1;
  int padcap = 8192;
  long bfit = avail / padcap;
  if (bfit < 1) { padcap = (int)avail; bfit = 1; }
  if (bfit > NBK) bfit = NBK;
  int npass = (int)((NBK + bfit - 1) / bfit);

  k_detect<<<1, 64, 0, stream>>>(input, boundary, relw, W, eweight,
                                 flags, bcurp);
  k_ew<<<(NE + 8191) / 8192, 256, 0, stream>>>(eweight, flags);

  const int PA_NB = (NE + CHUNK - 1) / CHUNK;
  for (int p = 0; p < npass; ++p) {
    int gb0 = (int)((long)NBK * p / npass);
    int gb1 = (int)((long)NBK * (p + 1) / npass);
    int hi = (gb1 * 128 < NN) ? gb1 * 128 : NN;
    k_parta<<<PA_NB, 256, 0, stream>>>(edges, bcurp, eidx, flags,
                                       gb0, gb1, padcap);
    k_node<<<gb1 - gb0, 1024, 0, stream>>>(
        input, boundary, edges, eweight, relw, W, bv, bcurp, eidx, flags,
        d_out, gb0, hi, padcap);
  }
}

// Round 10
// 213.773 us; speedup vs baseline: 7.1245x; 1.0506x over previous
//
#include <hip/hip_runtime.h>
#include <hip/hip_bf16.h>

#define NN  50000
#define NE  1600000
#define DIM 64
#define NBK 391          // 128-node buckets

// ---- ws layout (int32 offsets) -------------------------------------------
#define OFF_FLAGS  0            // 8 ints
#define OFF_BCURP  8            // 391*16 padded cursors (64B/bucket, atomics)
#define OFF_EIDX   6272         // padded records: [bucket][PADCAP]

#define CHUNK 4096   // edges per k_parta block
#define SBCAP 7936   // in-LDS sort capacity (expected max bucket ~4400)

typedef __bf16 bf16x8 __attribute__((ext_vector_type(8)));
typedef __bf16 bf16x4 __attribute__((ext_vector_type(4)));
typedef float  f32x4  __attribute__((ext_vector_type(4)));

__device__ __forceinline__ float loadF(const void* p, int i, int bf) {
  if (bf) return __bfloat162float(((const __hip_bfloat16*)p)[i]);
  return ((const float*)p)[i];
}

__device__ __forceinline__ float4 loadF4(const void* p, int i4, int bf) {
  if (bf) {
    ushort4 u = ((const ushort4*)p)[i4];
    float4 f;
    union { unsigned int ui; float fl; } c;
    c.ui = (unsigned int)u.x << 16; f.x = c.fl;
    c.ui = (unsigned int)u.y << 16; f.y = c.fl;
    c.ui = (unsigned int)u.z << 16; f.z = c.fl;
    c.ui = (unsigned int)u.w << 16; f.w = c.fl;
    return f;
  }
  return ((const float4*)p)[i4];
}

__device__ __forceinline__ void accumF(float4 a, float4 r,
                                       float4& s4, float4& q4) {
  float tx = a.x * r.x, ty = a.y * r.y, tz = a.z * r.z, tw = a.w * r.w;
  s4.x += tx; q4.x = fmaf(tx, tx, q4.x);
  s4.y += ty; q4.y = fmaf(ty, ty, q4.y);
  s4.z += tz; q4.z = fmaf(tz, tz, q4.z);
  s4.w += tw; q4.w = fmaf(tw, tw, q4.w);
}

// Per-array dtype detection + zero padded bucket cursors.
__global__ void k_detect(const void* input, const void* boundary,
                         const void* relw, const void* W, const void* ew,
                         int* flags, int* bcurp) {
  __shared__ int cnt;
  int t = threadIdx.x;  // 64 threads
  const void* arrs[4] = {input, boundary, relw, W};
  for (int a = 0; a < 4; ++a) {
    if (t == 0) cnt = 0;
    __syncthreads();
    const unsigned short* u = (const unsigned short*)arrs[a];
    unsigned ex = (u[2 * t] >> 7) & 0xFF;
    if (ex >= 100 && ex <= 140) atomicAdd(&cnt, 1);
    __syncthreads();
    if (t == 0) flags[a] = (cnt >= 32) ? 1 : 0;
    __syncthreads();
  }
  if (t == 0) {
    flags[4] = (((const unsigned short*)ew)[0] == 0x3F80) ? 1 : 0;
    flags[5] = 1;
  }
  for (int i = t; i < NBK * 16; i += 64) bcurp[i] = 0;
}

// Exact all-ones check of edge weights.
__global__ __launch_bounds__(256) void k_ew(const void* __restrict__ ew,
                                            int* __restrict__ flags) {
  int bfE = flags[4];
  int c0 = blockIdx.x * 8192;
  int bad = 0;
  for (int i = threadIdx.x; i < 8192; i += 256) {
    int e = c0 + i;
    if (e < NE && loadF(ew, e, bfE) != 1.0f) bad = 1;
  }
  if (bad) flags[5] = 0;
}

// Partition edges into PADDED per-bucket regions via LDS staging.
// v10: 1024 threads/block (R9's 256 gave only 1.5 waves/SIMD -> latency-
// bound); same 391 blocks so fixed NBK costs unchanged (R4 lesson). Edge
// triples read ONCE into registers (rec[4]/bb[4], static unroll) -- the
// second 19.2 MB el pass is gone.
__global__ __launch_bounds__(1024) void k_parta(
    const int* __restrict__ el, int* __restrict__ bcurp,
    int* __restrict__ eidx, const int* __restrict__ flags,
    int gb0, int gb1, int padcap) {
  __shared__ int stage[CHUNK];
  __shared__ unsigned short sbk[CHUNK];
  __shared__ int lh[NBK], lbase[NBK], lh2[NBK], gbs[NBK];
  __shared__ int sc[256];
  __shared__ int total;
  int t = threadIdx.x;
  int nb = gb1 - gb0;
  int c0 = blockIdx.x * CHUNK;
  int ones = flags[5];
  for (int i = t; i < nb; i += 1024) { lh[i] = 0; lh2[i] = 0; }
  __syncthreads();

  // pass 1: load triples once, keep rec/bucket in registers, histogram.
  int rec[4], bb[4];
  #pragma unroll
  for (int j = 0; j < 4; ++j) {
    int e = c0 + j * 1024 + t;
    bb[j] = -1; rec[j] = 0;
    if (e < NE) {
      int n0 = el[e * 3], n1 = el[e * 3 + 1], n2 = el[e * 3 + 2];
      int b = (n1 >> 7) - gb0;
      if (b >= 0 && b < nb) {
        bb[j] = b;
        rec[j] = ones ? (n0 | (n2 << 16) | ((n1 & 127) << 25))
                      : (e | ((n1 & 127) << 25));
        atomicAdd(&lh[b], 1);
      }
    }
  }
  __syncthreads();

  // scan (pair trick, first 256 threads), cursor atomics.
  int a0 = 0, a1 = 0;
  if (t < 256) {
    a0 = (2 * t < nb) ? lh[2 * t] : 0;
    a1 = (2 * t + 1 < nb) ? lh[2 * t + 1] : 0;
    sc[t] = a0 + a1;
  }
  __syncthreads();
  for (int off = 1; off < 256; off <<= 1) {
    int v = 0;
    if (t < 256 && t >= off) v = sc[t - off];
    __syncthreads();
    if (t < 256) sc[t] += v;
    __syncthreads();
  }
  if (t < 256) {
    int excl = sc[t] - (a0 + a1);
    if (2 * t < nb) {
      lbase[2 * t] = excl;
      if (a0 > 0) gbs[2 * t] = atomicAdd(&bcurp[(gb0 + 2 * t) * 16], a0);
    }
    if (2 * t + 1 < nb) {
      lbase[2 * t + 1] = excl + a0;
      if (a1 > 0)
        gbs[2 * t + 1] = atomicAdd(&bcurp[(gb0 + 2 * t + 1) * 16], a1);
    }
    if (t == 255) total = sc[255];
  }
  __syncthreads();

  // pass 2: scatter registers -> LDS stage (bucket-contiguous runs).
  #pragma unroll
  for (int j = 0; j < 4; ++j) {
    if (bb[j] >= 0) {
      int r = atomicAdd(&lh2[bb[j]], 1);
      int slot = lbase[bb[j]] + r;
      stage[slot] = rec[j];
      sbk[slot] = (unsigned short)bb[j];
    }
  }
  __syncthreads();

  // pass 3: coalesced run-writes to padded global regions.
  int tot = total;
  for (int i = t; i < tot; i += 1024) {
    int b = sbk[i];
    int slot = gbs[b] + (i - lbase[b]);
    if (slot < padcap) eidx[(long)b * padcap + slot] = stage[i];
  }
}

// Fused sort+node kernel (R7-R9 structure, 96us verified). One 1024-thread
// block = one 128-node bucket; in-LDS counting sort (ld -> ld2), then the
// proven edge phase (f32 gathers: R3 showed fp16 staging was time-neutral).
__global__ __launch_bounds__(1024, 8) void k_node(
    const void* __restrict__ input, const void* __restrict__ boundary,
    const int* __restrict__ el, const void* __restrict__ ew,
    const void* __restrict__ relw, const void* __restrict__ W,
    const void* __restrict__ bv, const int* __restrict__ bcurp,
    const int* __restrict__ eidx, const int* __restrict__ flags,
    void* __restrict__ out, int gb0, int hi, int padcap) {
  __shared__ int ld[SBCAP];     // raw records; aliased as updb after scatter
  __shared__ int ld2[SBCAP];    // node-sorted records
  __shared__ int lstart[128], lend[128], lcnt[128];
  __bf16 (*updb)[72] = reinterpret_cast<__bf16(*)[72]>(ld);

  int bfI = flags[0], bfB = flags[1], bfR = flags[2], bfW = flags[3],
      bfE = flags[4], ones = flags[5];
  int t = threadIdx.x;
  int wv = t >> 6, ln = t & 63;
  int g = ln >> 4;           // edge sub-slot group
  int k = ln & 15;           // float4 index within the 64-dim row
  int q = ln >> 4;
  int B = gb0 + blockIdx.x;
  int n0 = B * 128;
  int cnt = bcurp[B * 16];
  int fast = (cnt <= SBCAP) && (cnt <= padcap);
  const int* myeidx = eidx + (long)blockIdx.x * padcap;

  if (t < 128) lcnt[t] = 0;
  __syncthreads();
  if (fast) {
    for (int i = t; i < cnt; i += 1024) ld[i] = myeidx[i];
    __syncthreads();
    for (int i = t; i < cnt; i += 1024)
      atomicAdd(&lcnt[(((unsigned)ld[i]) >> 25) & 127], 1);
  }
  __syncthreads();
  // inclusive scan of lcnt in lend
  if (t < 128) lend[t] = lcnt[t];
  __syncthreads();
  for (int off = 1; off < 128; off <<= 1) {
    int v = 0;
    if (t < 128 && t >= off) v = lend[t - off];
    __syncthreads();
    if (t < 128) lend[t] += v;
    __syncthreads();
  }
  if (t < 128) { lstart[t] = lend[t] - lcnt[t]; lcnt[t] = 0; }
  __syncthreads();
  if (fast) {
    for (int i = t; i < cnt; i += 1024) {
      int rec = ld[i];
      int l = (((unsigned)rec) >> 25) & 127;
      int r = atomicAdd(&lcnt[l], 1);
      ld2[lstart[l] + r] = rec;
    }
  }
  __syncthreads();   // ld dead from here -> safe to alias as updb

  const float4* inp4 = (const float4*)input;
  const float4* rw4  = (const float4*)relw;
  int hot = (!bfI && !bfR && ones) ? 1 : 0;

  // ---- edge phase: 8 nodes per wave ----
  for (int rr = 0; rr < 8; ++rr) {
    int row = wv * 8 + rr;
    int n = n0 + row;
    if (n >= hi) {
      if (g == 0) *(bf16x4*)&updb[row][4 * k] =
          bf16x4{(__bf16)0.f, (__bf16)0.f, (__bf16)0.f, (__bf16)0.f};
      continue;
    }
    float4 s4 = {0.f,0.f,0.f,0.f}, q4 = {0.f,0.f,0.f,0.f};
    float degf = 0.f;
    if (fast) {
      int start = lstart[row], end = lend[row];
      degf = (float)(end - start);
      if (hot) {
        for (int base = start; base < end; base += 64) {
          int mm = end - base; if (mm > 64) mm = 64;
          int rec = 0;
          if (ln < mm) rec = ld2[base + ln];
          int jq = mm >> 2;
          int jmax = (mm + 3) >> 2;
          int j = 0;
          for (; j + 4 <= jq; j += 4) {   // 16 edges per iter
            int pk0 = __shfl(rec, j * 4 + g);
            int pk1 = __shfl(rec, j * 4 + 4 + g);
            int pk2 = __shfl(rec, j * 4 + 8 + g);
            int pk3 = __shfl(rec, j * 4 + 12 + g);
            float4 a0 = inp4[(pk0 & 0xFFFF) * 16 + k];
            float4 r0 = rw4[((pk0 >> 16) & 0x1FF) * 16 + k];
            float4 a1 = inp4[(pk1 & 0xFFFF) * 16 + k];
            float4 r1 = rw4[((pk1 >> 16) & 0x1FF) * 16 + k];
            float4 a2 = inp4[(pk2 & 0xFFFF) * 16 + k];
            float4 r2 = rw4[((pk2 >> 16) & 0x1FF) * 16 + k];
            float4 a3 = inp4[(pk3 & 0xFFFF) * 16 + k];
            float4 r3 = rw4[((pk3 >> 16) & 0x1FF) * 16 + k];
            accumF(a0, r0, s4, q4);
            accumF(a1, r1, s4, q4);
            accumF(a2, r2, s4, q4);
            accumF(a3, r3, s4, q4);
          }
          for (; j < jq; ++j) {
            int pk = __shfl(rec, j * 4 + g);
            float4 a = inp4[(pk & 0xFFFF) * 16 + k];
            float4 r = rw4[((pk >> 16) & 0x1FF) * 16 + k];
            accumF(a, r, s4, q4);
          }
          for (; j < jmax; ++j) {      // predicated tail (<=1 iter)
            int slot = j * 4 + g;
            int pk = __shfl(rec, slot & 63);
            float wsel = (slot < mm) ? 1.0f : 0.0f;
            float4 a = inp4[(pk & 0xFFFF) * 16 + k];
            float4 r = rw4[((pk >> 16) & 0x1FF) * 16 + k];
            float tx = a.x*r.x, ty = a.y*r.y, tz = a.z*r.z, tw = a.w*r.w;
            s4.x = fmaf(wsel, tx, s4.x); q4.x = fmaf(wsel*tx, tx, q4.x);
            s4.y = fmaf(wsel, ty, s4.y); q4.y = fmaf(wsel*ty, ty, q4.y);
            s4.z = fmaf(wsel, tz, s4.z); q4.z = fmaf(wsel*tz, tz, q4.z);
            s4.w = fmaf(wsel, tw, s4.w); q4.w = fmaf(wsel*tw, tw, q4.w);
          }
        }
      } else {
        for (int base = start; base < end; base += 64) {
          int mm = end - base; if (mm > 64) mm = 64;
          int rec = 0; float wrec = 0.0f;
          if (ln < mm) {
            rec = ld2[base + ln] & 0x1FFFFFF;
            if (!ones) wrec = loadF(ew, rec, bfE);
          }
          int jmax = (mm + 3) >> 2;
          for (int j = 0; j < jmax; ++j) {
            int slot = j * 4 + g;
            int rj = __shfl(rec, slot);
            int nin, rl; float wj;
            if (ones) { nin = rj & 0xFFFF; rl = (rj >> 16) & 0x1FF; wj = 1.0f; }
            else      { nin = el[rj * 3]; rl = el[rj * 3 + 2];
                        wj = __shfl(wrec, slot); }
            float wsel = (slot < mm) ? wj : 0.0f;
            float4 a = loadF4(input, nin * 16 + k, bfI);
            float4 r = loadF4(relw, rl * 16 + k, bfR);
            float tx = a.x*r.x, ty = a.y*r.y, tz = a.z*r.z, tw = a.w*r.w;
            s4.x = fmaf(wsel, tx, s4.x); q4.x = fmaf(wsel*tx, tx, q4.x);
            s4.y = fmaf(wsel, ty, s4.y); q4.y = fmaf(wsel*ty, ty, q4.y);
            s4.z = fmaf(wsel, tz, s4.z); q4.z = fmaf(wsel*tz, tz, q4.z);
            s4.w = fmaf(wsel, tw, s4.w); q4.w = fmaf(wsel*tw, tw, q4.w);
          }
        }
      }
    } else {
      // correctness-only fallback: scan full edge list for this node
      float degc = 0.f;
      for (int e0 = g; e0 < NE; e0 += 4) {
        int nout = el[e0 * 3 + 1];
        if (nout != n) continue;
        degc += 1.0f;
        int nin = el[e0 * 3], rl = el[e0 * 3 + 2];
        float wj = ones ? 1.0f : loadF(ew, e0, bfE);
        float4 a = loadF4(input, nin * 16 + k, bfI);
        float4 r = loadF4(relw, rl * 16 + k, bfR);
        float tx = wj*a.x*r.x, ty = wj*a.y*r.y, tz = wj*a.z*r.z,
              tw = wj*a.w*r.w;
        s4.x += tx; q4.x = fmaf(tx, tx, q4.x);
        s4.y += ty; q4.y = fmaf(ty, ty, q4.y);
        s4.z += tz; q4.z = fmaf(tz, tz, q4.z);
        s4.w += tw; q4.w = fmaf(tw, tw, q4.w);
      }
      degc += __shfl_xor(degc, 16); degc += __shfl_xor(degc, 32);
      degf = degc;
    }
    s4.x += __shfl_xor(s4.x, 16); s4.x += __shfl_xor(s4.x, 32);
    s4.y += __shfl_xor(s4.y, 16); s4.y += __shfl_xor(s4.y, 32);
    s4.z += __shfl_xor(s4.z, 16); s4.z += __shfl_xor(s4.z, 32);
    s4.w += __shfl_xor(s4.w, 16); s4.w += __shfl_xor(s4.w, 32);
    q4.x += __shfl_xor(q4.x, 16); q4.x += __shfl_xor(q4.x, 32);
    q4.y += __shfl_xor(q4.y, 16); q4.y += __shfl_xor(q4.y, 32);
    q4.z += __shfl_xor(q4.z, 16); q4.z += __shfl_xor(q4.z, 32);
    q4.w += __shfl_xor(q4.w, 16); q4.w += __shfl_xor(q4.w, 32);
    if (g == 0) {
      float4 b4 = loadF4(boundary, n * 16 + k, bfB);
      float dg = degf + 1.0f;
      float sv, qv;
      bf16x4 u;
      sv = (s4.x + b4.x) / dg; qv = (q4.x + b4.x * b4.x) / dg;
      u[0] = (__bf16)sqrtf(fmaxf(qv - sv * sv, 1e-6f));
      sv = (s4.y + b4.y) / dg; qv = (q4.y + b4.y * b4.y) / dg;
      u[1] = (__bf16)sqrtf(fmaxf(qv - sv * sv, 1e-6f));
      sv = (s4.z + b4.z) / dg; qv = (q4.z + b4.z * b4.z) / dg;
      u[2] = (__bf16)sqrtf(fmaxf(qv - sv * sv, 1e-6f));
      sv = (s4.w + b4.w) / dg; qv = (q4.w + b4.w * b4.w) / dg;
      u[3] = (__bf16)sqrtf(fmaxf(qv - sv * sv, 1e-6f));
      *(bf16x4*)&updb[row][4 * k] = u;
    }
  }
  __syncthreads();

  // ---- MFMA epilogue: wave wv -> node-tile wv>>1, col-half wv&1 ----
  int tt = wv >> 1, chh = wv & 1;
  bf16x8 af0 = *(const bf16x8*)&updb[tt * 16 + (ln & 15)][q * 8];
  bf16x8 af1 = *(const bf16x8*)&updb[tt * 16 + (ln & 15)][32 + q * 8];
  #pragma unroll
  for (int hh = 0; hh < 2; ++hh) {
    int cc = chh * 32 + hh * 16 + (ln & 15);
    bf16x8 bfr0, bfr1;
    #pragma unroll
    for (int j = 0; j < 8; ++j) {
      bfr0[j] = (__bf16)loadF(W, cc * 64 + q * 8 + j, bfW);
      bfr1[j] = (__bf16)loadF(W, cc * 64 + 32 + q * 8 + j, bfW);
    }
    float bias = loadF(bv, cc, bfW);
    f32x4 accv = {0.f, 0.f, 0.f, 0.f};
    accv = __builtin_amdgcn_mfma_f32_16x16x32_bf16(af0, bfr0, accv, 0, 0, 0);
    accv = __builtin_amdgcn_mfma_f32_16x16x32_bf16(af1, bfr1, accv, 0, 0, 0);
    #pragma unroll
    for (int i = 0; i < 4; ++i) {
      int nn = n0 + tt * 16 + q * 4 + i;
      if (nn < hi) {
        float v = accv[i] + bias;
        if (bfI) ((__hip_bfloat16*)out)[nn * 64 + cc] = __float2bfloat16(v);
        else     ((float*)out)[nn * 64 + cc] = v;
      }
    }
  }
}

extern "C" void kernel_launch(void* const* d_in, const int* in_sizes, int n_in,
                              void* d_out, int out_size, void* d_ws, size_t ws_size,
                              hipStream_t stream) {
  const void* input    = d_in[0];
  const void* boundary = d_in[1];
  const int*  edges    = (const int*)d_in[2];
  const void* eweight  = d_in[3];
  const void* relw     = d_in[4];
  const void* W        = d_in[5];
  const void* bv       = d_in[6];

  int* wsI    = (int*)d_ws;
  int* flags  = wsI + OFF_FLAGS;
  int* bcurp  = wsI + OFF_BCURP;
  int* eidx   = wsI + OFF_EIDX;

  long avail = (long)(ws_size / 4) - OFF_EIDX;
  if (avail < 1) avail = 1;
  int padcap = 8192;
  long bfit = avail / padcap;
  if (bfit < 1) { padcap = (int)avail; bfit = 1; }
  if (bfit > NBK) bfit = NBK;
  int npass = (int)((NBK + bfit - 1) / bfit);

  k_detect<<<1, 64, 0, stream>>>(input, boundary, relw, W, eweight,
                                 flags, bcurp);
  k_ew<<<(NE + 8191) / 8192, 256, 0, stream>>>(eweight, flags);

  const int PA_NB = (NE + CHUNK - 1) / CHUNK;
  for (int p = 0; p < npass; ++p) {
    int gb0 = (int)((long)NBK * p / npass);
    int gb1 = (int)((long)NBK * (p + 1) / npass);
    int hi = (gb1 * 128 < NN) ? gb1 * 128 : NN;
    k_parta<<<PA_NB, 1024, 0, stream>>>(edges, bcurp, eidx, flags,
                                        gb0, gb1, padcap);
    k_node<<<gb1 - gb0, 1024, 0, stream>>>(
        input, boundary, edges, eweight, relw, W, bv, bcurp, eidx, flags,
        d_out, gb0, hi, padcap);
  }
}

// Round 11
// 212.457 us; speedup vs baseline: 7.1686x; 1.0062x over previous
//
#include <hip/hip_runtime.h>
#include <hip/hip_bf16.h>

#define NN  50000
#define NE  1600000
#define DIM 64
#define NBK 391          // 128-node buckets

// ---- ws layout (int32 offsets) -------------------------------------------
#define OFF_FLAGS  0            // 8 ints
#define OFF_BCURP  8            // 391*16 padded cursors (64B/bucket, atomics)
#define OFF_EIDX   6272         // padded records: [bucket][PADCAP]

#define CHUNK 8192   // edges per k_parta block (R11: halves fixed NBK costs)
#define QCAP  2304   // per-quarter record capacity in k_node

typedef __bf16 bf16x8 __attribute__((ext_vector_type(8)));
typedef __bf16 bf16x4 __attribute__((ext_vector_type(4)));
typedef float  f32x4  __attribute__((ext_vector_type(4)));

__device__ __forceinline__ float loadF(const void* p, int i, int bf) {
  if (bf) return __bfloat162float(((const __hip_bfloat16*)p)[i]);
  return ((const float*)p)[i];
}

__device__ __forceinline__ float4 loadF4(const void* p, int i4, int bf) {
  if (bf) {
    ushort4 u = ((const ushort4*)p)[i4];
    float4 f;
    union { unsigned int ui; float fl; } c;
    c.ui = (unsigned int)u.x << 16; f.x = c.fl;
    c.ui = (unsigned int)u.y << 16; f.y = c.fl;
    c.ui = (unsigned int)u.z << 16; f.z = c.fl;
    c.ui = (unsigned int)u.w << 16; f.w = c.fl;
    return f;
  }
  return ((const float4*)p)[i4];
}

__device__ __forceinline__ void accumF(float4 a, float4 r,
                                       float4& s4, float4& q4) {
  float tx = a.x * r.x, ty = a.y * r.y, tz = a.z * r.z, tw = a.w * r.w;
  s4.x += tx; q4.x = fmaf(tx, tx, q4.x);
  s4.y += ty; q4.y = fmaf(ty, ty, q4.y);
  s4.z += tz; q4.z = fmaf(tz, tz, q4.z);
  s4.w += tw; q4.w = fmaf(tw, tw, q4.w);
}

// Per-array dtype detection + zero padded bucket cursors.
__global__ void k_detect(const void* input, const void* boundary,
                         const void* relw, const void* W, const void* ew,
                         int* flags, int* bcurp) {
  __shared__ int cnt;
  int t = threadIdx.x;  // 64 threads
  const void* arrs[4] = {input, boundary, relw, W};
  for (int a = 0; a < 4; ++a) {
    if (t == 0) cnt = 0;
    __syncthreads();
    const unsigned short* u = (const unsigned short*)arrs[a];
    unsigned ex = (u[2 * t] >> 7) & 0xFF;
    if (ex >= 100 && ex <= 140) atomicAdd(&cnt, 1);
    __syncthreads();
    if (t == 0) flags[a] = (cnt >= 32) ? 1 : 0;
    __syncthreads();
  }
  if (t == 0) {
    flags[4] = (((const unsigned short*)ew)[0] == 0x3F80) ? 1 : 0;
    flags[5] = 1;
  }
  for (int i = t; i < NBK * 16; i += 64) bcurp[i] = 0;
}

// Exact all-ones check of edge weights.
__global__ __launch_bounds__(256) void k_ew(const void* __restrict__ ew,
                                            int* __restrict__ flags) {
  int bfE = flags[4];
  int c0 = blockIdx.x * 8192;
  int bad = 0;
  for (int i = threadIdx.x; i < 8192; i += 256) {
    int e = c0 + i;
    if (e < NE && loadF(ew, e, bfE) != 1.0f) bad = 1;
  }
  if (bad) flags[5] = 0;
}

// Partition edges into PADDED per-bucket regions via LDS staging.
// R11: CHUNK 8192 (196 blocks) halves total fixed NBK cost (R4's mechanism
// in reverse) and doubles scatter run length (~21 ints -> full-line writes).
// Edge triples read ONCE into registers (rec[8]/bb[8], static unroll).
__global__ __launch_bounds__(1024) void k_parta(
    const int* __restrict__ el, int* __restrict__ bcurp,
    int* __restrict__ eidx, const int* __restrict__ flags,
    int gb0, int gb1, int padcap) {
  __shared__ int stage[CHUNK];              // 32 KB
  __shared__ unsigned short sbk[CHUNK];     // 16 KB
  __shared__ int lh[NBK], lbase[NBK], lh2[NBK], gbs[NBK];
  __shared__ int sc[256];
  __shared__ int total;
  int t = threadIdx.x;
  int nb = gb1 - gb0;
  int c0 = blockIdx.x * CHUNK;
  int ones = flags[5];
  for (int i = t; i < nb; i += 1024) { lh[i] = 0; lh2[i] = 0; }
  __syncthreads();

  // pass 1: load triples once, keep rec/bucket in registers, histogram.
  int rec[8], bb[8];
  #pragma unroll
  for (int j = 0; j < 8; ++j) {
    int e = c0 + j * 1024 + t;
    bb[j] = -1; rec[j] = 0;
    if (e < NE) {
      int n0 = el[e * 3], n1 = el[e * 3 + 1], n2 = el[e * 3 + 2];
      int b = (n1 >> 7) - gb0;
      if (b >= 0 && b < nb) {
        bb[j] = b;
        rec[j] = ones ? (n0 | (n2 << 16) | ((n1 & 127) << 25))
                      : (e | ((n1 & 127) << 25));
        atomicAdd(&lh[b], 1);
      }
    }
  }
  __syncthreads();

  // scan (pair trick, first 256 threads), cursor atomics.
  int a0 = 0, a1 = 0;
  if (t < 256) {
    a0 = (2 * t < nb) ? lh[2 * t] : 0;
    a1 = (2 * t + 1 < nb) ? lh[2 * t + 1] : 0;
    sc[t] = a0 + a1;
  }
  __syncthreads();
  for (int off = 1; off < 256; off <<= 1) {
    int v = 0;
    if (t < 256 && t >= off) v = sc[t - off];
    __syncthreads();
    if (t < 256) sc[t] += v;
    __syncthreads();
  }
  if (t < 256) {
    int excl = sc[t] - (a0 + a1);
    if (2 * t < nb) {
      lbase[2 * t] = excl;
      if (a0 > 0) gbs[2 * t] = atomicAdd(&bcurp[(gb0 + 2 * t) * 16], a0);
    }
    if (2 * t + 1 < nb) {
      lbase[2 * t + 1] = excl + a0;
      if (a1 > 0)
        gbs[2 * t + 1] = atomicAdd(&bcurp[(gb0 + 2 * t + 1) * 16], a1);
    }
    if (t == 255) total = sc[255];
  }
  __syncthreads();

  // pass 2: scatter registers -> LDS stage (bucket-contiguous runs).
  #pragma unroll
  for (int j = 0; j < 8; ++j) {
    if (bb[j] >= 0) {
      int r = atomicAdd(&lh2[bb[j]], 1);
      int slot = lbase[bb[j]] + r;
      stage[slot] = rec[j];
      sbk[slot] = (unsigned short)bb[j];
    }
  }
  __syncthreads();

  // pass 3: coalesced run-writes to padded global regions.
  int tot = total;
  for (int i = t; i < tot; i += 1024) {
    int b = sbk[i];
    int slot = gbs[b] + (i - lbase[b]);
    if (slot < padcap) eidx[(long)b * padcap + slot] = stage[i];
  }
}

// R11 k_node: quarter-split. 4 blocks per 128-node bucket (grid 4x391=1564,
// 256 threads, ~19 KB LDS -> 8 blocks/CU all-resident; fixes the 1.53
// blocks/CU tail that capped R10's k_node at 76% grid efficiency).
// Each block filters the bucket region by record bits 30..31 (local>>5),
// counting-sorts its ~1024 records over 32 bins, runs the proven edge
// phase for its 32 nodes, then a 2-tile MFMA epilogue.
__global__ __launch_bounds__(256, 8) void k_node(
    const void* __restrict__ input, const void* __restrict__ boundary,
    const int* __restrict__ el, const void* __restrict__ ew,
    const void* __restrict__ relw, const void* __restrict__ W,
    const void* __restrict__ bv, const int* __restrict__ bcurp,
    const int* __restrict__ eidx, const int* __restrict__ flags,
    void* __restrict__ out, int gb0, int hi, int padcap) {
  __shared__ int ld[QCAP];      // filtered records; aliased as updb later
  __shared__ int ld2[QCAP];     // node-sorted records
  __shared__ int lstart[32], lend[32], lcnt[32];
  __shared__ int nf, ovf;
  __bf16 (*updb)[72] = reinterpret_cast<__bf16(*)[72]>(ld);

  int bfI = flags[0], bfB = flags[1], bfR = flags[2], bfW = flags[3],
      bfE = flags[4], ones = flags[5];
  int t = threadIdx.x;
  int wv = t >> 6, ln = t & 63;
  int g = ln >> 4;           // edge sub-slot group
  int k = ln & 15;           // float4 index within the 64-dim row
  int q = ln >> 4;
  int Bl = blockIdx.x >> 2;            // local bucket index
  int B  = gb0 + Bl;
  int quarter = blockIdx.x & 3;
  int n0 = B * 128 + quarter * 32;
  int cnt = bcurp[B * 16];
  const int* myeidx = eidx + (long)Bl * padcap;

  if (t == 0) { nf = 0; ovf = (cnt > padcap) ? 1 : 0; }
  if (t < 32) lcnt[t] = 0;
  __syncthreads();

  // filter bucket records belonging to this quarter (order arbitrary: the
  // per-node sum is commutative; counting sort below restores node grouping)
  int cl = cnt < padcap ? cnt : padcap;
  for (int i = t; i < cl; i += 256) {
    int rc = myeidx[i];
    if ((((unsigned)rc) >> 30) == (unsigned)quarter) {
      int p = atomicAdd(&nf, 1);
      if (p < QCAP) ld[p] = rc; else ovf = 1;   // benign same-value race
    }
  }
  __syncthreads();
  int fast = !ovf;
  int nq = nf < QCAP ? nf : QCAP;

  if (fast) {
    for (int i = t; i < nq; i += 256)
      atomicAdd(&lcnt[(((unsigned)ld[i]) >> 25) & 31], 1);
  }
  __syncthreads();
  if (t < 32) lend[t] = lcnt[t];
  __syncthreads();
  for (int off = 1; off < 32; off <<= 1) {
    int v = 0;
    if (t < 32 && t >= off) v = lend[t - off];
    __syncthreads();
    if (t < 32) lend[t] += v;
    __syncthreads();
  }
  if (t < 32) { lstart[t] = lend[t] - lcnt[t]; lcnt[t] = 0; }
  __syncthreads();
  if (fast) {
    for (int i = t; i < nq; i += 256) {
      int rc = ld[i];
      int l = (((unsigned)rc) >> 25) & 31;
      int r = atomicAdd(&lcnt[l], 1);
      ld2[lstart[l] + r] = rc;
    }
  }
  __syncthreads();   // ld dead from here -> safe to alias as updb

  const float4* inp4 = (const float4*)input;
  const float4* rw4  = (const float4*)relw;
  int hot = (!bfI && !bfR && ones) ? 1 : 0;

  // ---- edge phase: 8 nodes per wave (4 waves x 8 = 32 nodes) ----
  for (int rr = 0; rr < 8; ++rr) {
    int row = wv * 8 + rr;
    int n = n0 + row;
    if (n >= hi) {
      if (g == 0) *(bf16x4*)&updb[row][4 * k] =
          bf16x4{(__bf16)0.f, (__bf16)0.f, (__bf16)0.f, (__bf16)0.f};
      continue;
    }
    float4 s4 = {0.f,0.f,0.f,0.f}, q4 = {0.f,0.f,0.f,0.f};
    float degf = 0.f;
    if (fast) {
      int start = lstart[row], end = lend[row];
      degf = (float)(end - start);
      if (hot) {
        for (int base = start; base < end; base += 64) {
          int mm = end - base; if (mm > 64) mm = 64;
          int rec = 0;
          if (ln < mm) rec = ld2[base + ln];
          int jq = mm >> 2;
          int jmax = (mm + 3) >> 2;
          int j = 0;
          for (; j + 4 <= jq; j += 4) {   // 16 edges per iter
            int pk0 = __shfl(rec, j * 4 + g);
            int pk1 = __shfl(rec, j * 4 + 4 + g);
            int pk2 = __shfl(rec, j * 4 + 8 + g);
            int pk3 = __shfl(rec, j * 4 + 12 + g);
            float4 a0 = inp4[(pk0 & 0xFFFF) * 16 + k];
            float4 r0 = rw4[((pk0 >> 16) & 0x1FF) * 16 + k];
            float4 a1 = inp4[(pk1 & 0xFFFF) * 16 + k];
            float4 r1 = rw4[((pk1 >> 16) & 0x1FF) * 16 + k];
            float4 a2 = inp4[(pk2 & 0xFFFF) * 16 + k];
            float4 r2 = rw4[((pk2 >> 16) & 0x1FF) * 16 + k];
            float4 a3 = inp4[(pk3 & 0xFFFF) * 16 + k];
            float4 r3 = rw4[((pk3 >> 16) & 0x1FF) * 16 + k];
            accumF(a0, r0, s4, q4);
            accumF(a1, r1, s4, q4);
            accumF(a2, r2, s4, q4);
            accumF(a3, r3, s4, q4);
          }
          for (; j < jq; ++j) {
            int pk = __shfl(rec, j * 4 + g);
            float4 a = inp4[(pk & 0xFFFF) * 16 + k];
            float4 r = rw4[((pk >> 16) & 0x1FF) * 16 + k];
            accumF(a, r, s4, q4);
          }
          for (; j < jmax; ++j) {      // predicated tail (<=1 iter)
            int slot = j * 4 + g;
            int pk = __shfl(rec, slot & 63);
            float wsel = (slot < mm) ? 1.0f : 0.0f;
            float4 a = inp4[(pk & 0xFFFF) * 16 + k];
            float4 r = rw4[((pk >> 16) & 0x1FF) * 16 + k];
            float tx = a.x*r.x, ty = a.y*r.y, tz = a.z*r.z, tw = a.w*r.w;
            s4.x = fmaf(wsel, tx, s4.x); q4.x = fmaf(wsel*tx, tx, q4.x);
            s4.y = fmaf(wsel, ty, s4.y); q4.y = fmaf(wsel*ty, ty, q4.y);
            s4.z = fmaf(wsel, tz, s4.z); q4.z = fmaf(wsel*tz, tz, q4.z);
            s4.w = fmaf(wsel, tw, s4.w); q4.w = fmaf(wsel*tw, tw, q4.w);
          }
        }
      } else {
        for (int base = start; base < end; base += 64) {
          int mm = end - base; if (mm > 64) mm = 64;
          int rec = 0; float wrec = 0.0f;
          if (ln < mm) {
            rec = ld2[base + ln] & 0x1FFFFFF;
            if (!ones) wrec = loadF(ew, rec, bfE);
          }
          int jmax = (mm + 3) >> 2;
          for (int j = 0; j < jmax; ++j) {
            int slot = j * 4 + g;
            int rj = __shfl(rec, slot);
            int nin, rl; float wj;
            if (ones) { nin = rj & 0xFFFF; rl = (rj >> 16) & 0x1FF; wj = 1.0f; }
            else      { nin = el[rj * 3]; rl = el[rj * 3 + 2];
                        wj = __shfl(wrec, slot); }
            float wsel = (slot < mm) ? wj : 0.0f;
            float4 a = loadF4(input, nin * 16 + k, bfI);
            float4 r = loadF4(relw, rl * 16 + k, bfR);
            float tx = a.x*r.x, ty = a.y*r.y, tz = a.z*r.z, tw = a.w*r.w;
            s4.x = fmaf(wsel, tx, s4.x); q4.x = fmaf(wsel*tx, tx, q4.x);
            s4.y = fmaf(wsel, ty, s4.y); q4.y = fmaf(wsel*ty, ty, q4.y);
            s4.z = fmaf(wsel, tz, s4.z); q4.z = fmaf(wsel*tz, tz, q4.z);
            s4.w = fmaf(wsel, tw, s4.w); q4.w = fmaf(wsel*tw, tw, q4.w);
          }
        }
      }
    } else {
      // correctness-only fallback: scan full edge list for this node
      float degc = 0.f;
      for (int e0 = g; e0 < NE; e0 += 4) {
        int nout = el[e0 * 3 + 1];
        if (nout != n) continue;
        degc += 1.0f;
        int nin = el[e0 * 3], rl = el[e0 * 3 + 2];
        float wj = ones ? 1.0f : loadF(ew, e0, bfE);
        float4 a = loadF4(input, nin * 16 + k, bfI);
        float4 r = loadF4(relw, rl * 16 + k, bfR);
        float tx = wj*a.x*r.x, ty = wj*a.y*r.y, tz = wj*a.z*r.z,
              tw = wj*a.w*r.w;
        s4.x += tx; q4.x = fmaf(tx, tx, q4.x);
        s4.y += ty; q4.y = fmaf(ty, ty, q4.y);
        s4.z += tz; q4.z = fmaf(tz, tz, q4.z);
        s4.w += tw; q4.w = fmaf(tw, tw, q4.w);
      }
      degc += __shfl_xor(degc, 16); degc += __shfl_xor(degc, 32);
      degf = degc;
    }
    s4.x += __shfl_xor(s4.x, 16); s4.x += __shfl_xor(s4.x, 32);
    s4.y += __shfl_xor(s4.y, 16); s4.y += __shfl_xor(s4.y, 32);
    s4.z += __shfl_xor(s4.z, 16); s4.z += __shfl_xor(s4.z, 32);
    s4.w += __shfl_xor(s4.w, 16); s4.w += __shfl_xor(s4.w, 32);
    q4.x += __shfl_xor(q4.x, 16); q4.x += __shfl_xor(q4.x, 32);
    q4.y += __shfl_xor(q4.y, 16); q4.y += __shfl_xor(q4.y, 32);
    q4.z += __shfl_xor(q4.z, 16); q4.z += __shfl_xor(q4.z, 32);
    q4.w += __shfl_xor(q4.w, 16); q4.w += __shfl_xor(q4.w, 32);
    if (g == 0) {
      float4 b4 = loadF4(boundary, n * 16 + k, bfB);
      float dg = degf + 1.0f;
      float sv, qv;
      bf16x4 u;
      sv = (s4.x + b4.x) / dg; qv = (q4.x + b4.x * b4.x) / dg;
      u[0] = (__bf16)sqrtf(fmaxf(qv - sv * sv, 1e-6f));
      sv = (s4.y + b4.y) / dg; qv = (q4.y + b4.y * b4.y) / dg;
      u[1] = (__bf16)sqrtf(fmaxf(qv - sv * sv, 1e-6f));
      sv = (s4.z + b4.z) / dg; qv = (q4.z + b4.z * b4.z) / dg;
      u[2] = (__bf16)sqrtf(fmaxf(qv - sv * sv, 1e-6f));
      sv = (s4.w + b4.w) / dg; qv = (q4.w + b4.w * b4.w) / dg;
      u[3] = (__bf16)sqrtf(fmaxf(qv - sv * sv, 1e-6f));
      *(bf16x4*)&updb[row][4 * k] = u;
    }
  }
  __syncthreads();

  // ---- MFMA epilogue: 4 waves, 2 tiles; wave wv -> tile wv>>1, half wv&1 --
  int tt = wv >> 1, chh = wv & 1;
  bf16x8 af0 = *(const bf16x8*)&updb[tt * 16 + (ln & 15)][q * 8];
  bf16x8 af1 = *(const bf16x8*)&updb[tt * 16 + (ln & 15)][32 + q * 8];
  #pragma unroll
  for (int hh = 0; hh < 2; ++hh) {
    int cc = chh * 32 + hh * 16 + (ln & 15);
    bf16x8 bfr0, bfr1;
    #pragma unroll
    for (int j = 0; j < 8; ++j) {
      bfr0[j] = (__bf16)loadF(W, cc * 64 + q * 8 + j, bfW);
      bfr1[j] = (__bf16)loadF(W, cc * 64 + 32 + q * 8 + j, bfW);
    }
    float bias = loadF(bv, cc, bfW);
    f32x4 accv = {0.f, 0.f, 0.f, 0.f};
    accv = __builtin_amdgcn_mfma_f32_16x16x32_bf16(af0, bfr0, accv, 0, 0, 0);
    accv = __builtin_amdgcn_mfma_f32_16x16x32_bf16(af1, bfr1, accv, 0, 0, 0);
    #pragma unroll
    for (int i = 0; i < 4; ++i) {
      int nn = n0 + tt * 16 + q * 4 + i;
      if (nn < hi) {
        float v = accv[i] + bias;
        if (bfI) ((__hip_bfloat16*)out)[nn * 64 + cc] = __float2bfloat16(v);
        else     ((float*)out)[nn * 64 + cc] = v;
      }
    }
  }
}

extern "C" void kernel_launch(void* const* d_in, const int* in_sizes, int n_in,
                              void* d_out, int out_size, void* d_ws, size_t ws_size,
                              hipStream_t stream) {
  const void* input    = d_in[0];
  const void* boundary = d_in[1];
  const int*  edges    = (const int*)d_in[2];
  const void* eweight  = d_in[3];
  const void* relw     = d_in[4];
  const void* W        = d_in[5];
  const void* bv       = d_in[6];

  int* wsI    = (int*)d_ws;
  int* flags  = wsI + OFF_FLAGS;
  int* bcurp  = wsI + OFF_BCURP;
  int* eidx   = wsI + OFF_EIDX;

  long avail = (long)(ws_size / 4) - OFF_EIDX;
  if (avail < 1) avail = 1;
  int padcap = 8192;
  long bfit = avail / padcap;
  if (bfit < 1) { padcap = (int)avail; bfit = 1; }
  if (bfit > NBK) bfit = NBK;
  int npass = (int)((NBK + bfit - 1) / bfit);

  k_detect<<<1, 64, 0, stream>>>(input, boundary, relw, W, eweight,
                                 flags, bcurp);
  k_ew<<<(NE + 8191) / 8192, 256, 0, stream>>>(eweight, flags);

  const int PA_NB = (NE + CHUNK - 1) / CHUNK;
  for (int p = 0; p < npass; ++p) {
    int gb0 = (int)((long)NBK * p / npass);
    int gb1 = (int)((long)NBK * (p + 1) / npass);
    int hi = (gb1 * 128 < NN) ? gb1 * 128 : NN;
    k_parta<<<PA_NB, 1024, 0, stream>>>(edges, bcurp, eidx, flags,
                                        gb0, gb1, padcap);
    k_node<<<(gb1 - gb0) * 4, 256, 0, stream>>>(
        input, boundary, edges, eweight, relw, W, bv, bcurp, eidx, flags,
        d_out, gb0, hi, padcap);
  }
}